// Round 5
// baseline (22052.028 us; speedup 1.0000x reference)
//
#include <hip/hip_runtime.h>

// Seq2Seq GRU + Bahdanau attention, fp32. B=32 S=64 T=48 E=512 H=1024 V=32000.
// R5: persistent recurrence with ROTATION buffers: every cross-block value is
// written (write-through sc0sc1) to a fresh per-step address and read with
// plain cached (nt) loads — consumer L2 can't be stale on a never-seen line.
// Weights stay L2-resident (no bypass, no invalidation). 2-level grid barrier.
// launch_bounds(512,1): 256-VGPR budget, no spills (R4's 2.3GB spill traffic).

#define BB 32
#define SS 64
#define TT 48
#define TD 47
#define EE 512
#define HH 1024
#define GG 3072
#define VV 32000
#define SOS_IDX 1
#define NBE 128          // encoder blocks (8 j-cols each)
#define NBG 128          // decoder GRU blocks (8 j-cols each)
#define NBA 32           // decoder attention blocks (1 batch each)
#define NBD (NBG + NBA)
#define NTHR 512

typedef float f32x4 __attribute__((ext_vector_type(4)));

static __device__ __forceinline__ float sigmoid_f(float x) {
    return 1.0f / (1.0f + __expf(-x));
}
static __device__ __forceinline__ float tanh_f(float x) {
    return 1.0f - 2.0f / (__expf(2.0f * x) + 1.0f);
}
static __device__ __forceinline__ f32x4 ntld4(const float* p) {
    return __builtin_nontemporal_load((const f32x4*)p);
}
// write-through store: reaches the L3 coherence point (drained by vmcnt before
// barrier arrival); consumers' L2 miss-fills then see it.
static __device__ __forceinline__ void cstore(float* p, float v) {
    __hip_atomic_store(p, v, __ATOMIC_RELAXED, __HIP_MEMORY_SCOPE_AGENT);
}

// Two-level monotonic grid barrier: 8 leaf counters (by bid&7) + 1 root.
// No acquire/release fences -> no L2 writeback/invalidate -> weights stay warm.
static __device__ __forceinline__ void gbar(int* bar, int leafsz, int& bstep) {
    asm volatile("s_waitcnt vmcnt(0) lgkmcnt(0)" ::: "memory");
    __syncthreads();
    bstep += 1;
    if (threadIdx.x == 0) {
        int* leaf = bar + (blockIdx.x & 7) * 32;
        int* root = bar + 512;
        int lv = __hip_atomic_fetch_add(leaf, 1, __ATOMIC_RELAXED, __HIP_MEMORY_SCOPE_AGENT) + 1;
        if (lv == bstep * leafsz) {
            __hip_atomic_fetch_add(root, 1, __ATOMIC_RELAXED, __HIP_MEMORY_SCOPE_AGENT);
        }
        while (__hip_atomic_load(root, __ATOMIC_RELAXED, __HIP_MEMORY_SCOPE_AGENT) < bstep * 8) {
            __builtin_amdgcn_s_sleep(1);
        }
    }
    __syncthreads();
    asm volatile("" ::: "memory");
}

__global__ void k_dec_idx(const int* __restrict__ tgt, int* __restrict__ idx) {
    int m = blockIdx.x * 256 + threadIdx.x;
    if (m < TD * BB) {
        int t = m >> 5, b = m & 31;
        idx[m] = (t == 0) ? SOS_IDX : tgt[b * TT + t];
    }
}

// C[m,n] = sum_k A[row(m),k] * Wt[n,k] + bias[n]
__global__ __launch_bounds__(256) void k_gemm(
    const float* __restrict__ A, const float* __restrict__ Wt,
    const float* __restrict__ bias, float* __restrict__ C,
    const int* __restrict__ rowidx,
    int M, int N, int K, int lda, int ldw, int ldc, int permute)
{
    __shared__ __align__(16) float As[16][64];
    __shared__ __align__(16) float Bs[16][64];
    const int tid = threadIdx.x;
    const int tm = tid >> 4;
    const int tn = tid & 15;
    const int row0 = blockIdx.y * 64;
    const int col0 = blockIdx.x * 64;
    const int lr = tid >> 2;
    const int lq = tid & 3;

    long arow_off = -1;
    {
        int arow = row0 + lr;
        if (arow < M) {
            int r = rowidx ? rowidx[arow] : arow;
            arow_off = (long)r * lda;
        }
    }
    long wrow_off = -1;
    {
        int wcol = col0 + lr;
        if (wcol < N) wrow_off = (long)wcol * ldw;
    }

    float acc[4][4];
#pragma unroll
    for (int i = 0; i < 4; ++i)
#pragma unroll
        for (int j = 0; j < 4; ++j) acc[i][j] = 0.f;

    for (int k0 = 0; k0 < K; k0 += 16) {
        float4 av = make_float4(0.f, 0.f, 0.f, 0.f);
        if (arow_off >= 0) av = *(const float4*)(A + arow_off + k0 + lq * 4);
        float4 wv = make_float4(0.f, 0.f, 0.f, 0.f);
        if (wrow_off >= 0) wv = *(const float4*)(Wt + wrow_off + k0 + lq * 4);
        __syncthreads();
        As[lq * 4 + 0][lr] = av.x; As[lq * 4 + 1][lr] = av.y;
        As[lq * 4 + 2][lr] = av.z; As[lq * 4 + 3][lr] = av.w;
        Bs[lq * 4 + 0][lr] = wv.x; Bs[lq * 4 + 1][lr] = wv.y;
        Bs[lq * 4 + 2][lr] = wv.z; Bs[lq * 4 + 3][lr] = wv.w;
        __syncthreads();
#pragma unroll
        for (int kk = 0; kk < 16; ++kk) {
            float4 a4 = *(const float4*)&As[kk][tm * 4];
            float4 b4 = *(const float4*)&Bs[kk][tn * 4];
            acc[0][0] += a4.x * b4.x; acc[0][1] += a4.x * b4.y;
            acc[0][2] += a4.x * b4.z; acc[0][3] += a4.x * b4.w;
            acc[1][0] += a4.y * b4.x; acc[1][1] += a4.y * b4.y;
            acc[1][2] += a4.y * b4.z; acc[1][3] += a4.y * b4.w;
            acc[2][0] += a4.z * b4.x; acc[2][1] += a4.z * b4.y;
            acc[2][2] += a4.z * b4.z; acc[2][3] += a4.z * b4.w;
            acc[3][0] += a4.w * b4.x; acc[3][1] += a4.w * b4.y;
            acc[3][2] += a4.w * b4.z; acc[3][3] += a4.w * b4.w;
        }
    }

    float4 bv = make_float4(0.f, 0.f, 0.f, 0.f);
    if (bias) bv = *(const float4*)(bias + col0 + tn * 4);
#pragma unroll
    for (int i = 0; i < 4; ++i) {
        int m = row0 + tm * 4 + i;
        if (m >= M) continue;
        int orow = permute ? ((m & 31) * TD + (m >> 5)) : m;
        float4 v;
        v.x = acc[i][0] + bv.x; v.y = acc[i][1] + bv.y;
        v.z = acc[i][2] + bv.z; v.w = acc[i][3] + bv.w;
        *(float4*)(C + (long)orow * ldc + col0 + tn * 4) = v;
    }
}

// ---------------- persistent encoder ----------------
// Rotation: h_{s+1} lives at enc_out[:, s, :]. Block owns 8 j-cols.
// Thread = (b = tid&31, ks = tid>>5 in 0..15, kc = ks*64).
__global__ __launch_bounds__(NTHR, 1) void p_enc(
    const float* __restrict__ gi, const float* __restrict__ Whh,
    const float* __restrict__ bhh, float* __restrict__ enc_out, int* bar)
{
    __shared__ float red[24][16][32];
    const int tid = threadIdx.x, bid = blockIdx.x;
    const int b = tid & 31, ks = tid >> 5;
    const int j0 = bid * 8;
    const int kc = ks * 64;
    int bstep = 0;

    const float* w0 = Whh + ((size_t)j0 << 10) + kc;
    const float* w1 = Whh + ((size_t)(HH + j0) << 10) + kc;
    const float* w2 = Whh + ((size_t)(2 * HH + j0) << 10) + kc;

    for (int s = 0; s < SS; ++s) {
        float acc[24];
#pragma unroll
        for (int u = 0; u < 24; ++u) acc[u] = 0.f;
        if (s > 0) {
            f32x4 hreg[16];
            const float* hb = enc_out + ((size_t)b * SS + (s - 1)) * HH + kc;
#pragma unroll
            for (int i = 0; i < 16; ++i) hreg[i] = ntld4(hb + (i << 2));
#pragma unroll
            for (int i = 0; i < 16; ++i) {
                f32x4 h4 = hreg[i];
#pragma unroll
                for (int jj = 0; jj < 8; ++jj) {
                    f32x4 a4 = *(const f32x4*)(w0 + ((size_t)jj << 10) + (i << 2));
                    acc[jj] += h4.x * a4.x + h4.y * a4.y + h4.z * a4.z + h4.w * a4.w;
                    f32x4 b4 = *(const f32x4*)(w1 + ((size_t)jj << 10) + (i << 2));
                    acc[8 + jj] += h4.x * b4.x + h4.y * b4.y + h4.z * b4.z + h4.w * b4.w;
                    f32x4 c4 = *(const f32x4*)(w2 + ((size_t)jj << 10) + (i << 2));
                    acc[16 + jj] += h4.x * c4.x + h4.y * c4.y + h4.z * c4.z + h4.w * c4.w;
                }
            }
        }
#pragma unroll
        for (int u = 0; u < 24; ++u) red[u][ks][b] = acc[u];
        __syncthreads();
        if (tid < 256) {
            const int fj = tid >> 5, fb = tid & 31, j = j0 + fj;
            float s0 = 0.f, s1 = 0.f, s2 = 0.f;
#pragma unroll
            for (int q = 0; q < 16; ++q) {
                s0 += red[fj][q][fb];
                s1 += red[8 + fj][q][fb];
                s2 += red[16 + fj][q][fb];
            }
            const float* gr = gi + (size_t)(fb * SS + s) * GG;
            float g0 = __builtin_nontemporal_load(gr + j);
            float g1 = __builtin_nontemporal_load(gr + HH + j);
            float g2 = __builtin_nontemporal_load(gr + 2 * HH + j);
            float r = sigmoid_f(g0 + s0 + bhh[j]);
            float z = sigmoid_f(g1 + s1 + bhh[HH + j]);
            float n = tanh_f(g2 + r * (s2 + bhh[2 * HH + j]));
            float hold = (s > 0)
                ? __builtin_nontemporal_load(enc_out + ((size_t)fb * SS + (s - 1)) * HH + j)
                : 0.f;
            float hnew = (1.f - z) * n + z * hold;
            cstore(enc_out + ((size_t)fb * SS + s) * HH + j, hnew);
        }
        gbar(bar, NBE / 8, bstep);
    }
}

// ---------------- persistent decoder ----------------
// Rotation: h_{t+1} at h2all[t]; ctx_t at ctxroll[t]; q_t at qroll[t].
// blocks 0..127: GRU+q (8 j-cols). blocks 128..159: attention (1 batch each).
__global__ __launch_bounds__(NTHR, 1) void p_dec(
    const float* __restrict__ gi, const float* __restrict__ Whh,
    const float* __restrict__ bhh, const float* __restrict__ Wih,
    const float* __restrict__ wq, const float* __restrict__ bq,
    const float* __restrict__ keys, const float* __restrict__ wsv,
    const float* __restrict__ bsv, const int* __restrict__ src,
    const float* __restrict__ enc_out, float* __restrict__ h2all,
    float* __restrict__ qroll, float* __restrict__ ctxroll,
    float* __restrict__ attn_out, int* bar)
{
    __shared__ float red[24][16][32];     // 48 KB (GRU role)
    __shared__ float shs[3][8][32];
    __shared__ float qs[HH];
    __shared__ float wss[HH];
    __shared__ float sc[8][64];
    __shared__ float wl[64];
    const int tid = threadIdx.x, bid = blockIdx.x;
    const bool isg = bid < NBG;
    int bstep = 0;

    const int b = tid & 31, ks = tid >> 5;
    const int kc = ks * 64;
    const int j0 = bid * 8;
    const int ab = bid - NBG;

    const float* w0 = Whh + ((size_t)j0 << 10) + kc;
    const float* w1 = Whh + ((size_t)(HH + j0) << 10) + kc;
    const float* w2 = Whh + ((size_t)(2 * HH + j0) << 10) + kc;
    const float* wqb = wq + ((size_t)j0 << 10) + kc;
    const float* x0 = Wih + (size_t)(j0) * (EE + HH) + EE + kc;
    const float* x1 = Wih + (size_t)(HH + j0) * (EE + HH) + EE + kc;
    const float* x2 = Wih + (size_t)(2 * HH + j0) * (EE + HH) + EE + kc;

    if (!isg) {
        for (int i = tid; i < HH; i += NTHR) wss[i] = wsv[i];
    }

    for (int t = 0; t < TD; ++t) {
        // ===== P1: GRU blocks: h-side gate dots + q-slice =====
        if (isg) {
            const float* hb = (t == 0)
                ? enc_out + ((size_t)b * SS + (SS - 1)) * HH + kc
                : h2all + ((size_t)(t - 1) * BB + b) * HH + kc;
            f32x4 hreg[16];
#pragma unroll
            for (int i = 0; i < 16; ++i) hreg[i] = ntld4(hb + (i << 2));
            // pass A: gates r, z
            float acc[16];
#pragma unroll
            for (int u = 0; u < 16; ++u) acc[u] = 0.f;
#pragma unroll
            for (int i = 0; i < 16; ++i) {
                f32x4 h4 = hreg[i];
#pragma unroll
                for (int jj = 0; jj < 8; ++jj) {
                    f32x4 a4 = *(const f32x4*)(w0 + ((size_t)jj << 10) + (i << 2));
                    acc[jj] += h4.x * a4.x + h4.y * a4.y + h4.z * a4.z + h4.w * a4.w;
                    f32x4 b4 = *(const f32x4*)(w1 + ((size_t)jj << 10) + (i << 2));
                    acc[8 + jj] += h4.x * b4.x + h4.y * b4.y + h4.z * b4.z + h4.w * b4.w;
                }
            }
#pragma unroll
            for (int u = 0; u < 16; ++u) red[u][ks][b] = acc[u];
            __syncthreads();
            if (tid < 256) {
                const int fj = tid >> 5, fb = tid & 31;
                float s0 = 0.f, s1 = 0.f;
#pragma unroll
                for (int q = 0; q < 16; ++q) {
                    s0 += red[fj][q][fb];
                    s1 += red[8 + fj][q][fb];
                }
                shs[0][fj][fb] = s0;
                shs[1][fj][fb] = s1;
            }
            __syncthreads();
            // pass B: gate n + q
#pragma unroll
            for (int u = 0; u < 16; ++u) acc[u] = 0.f;
#pragma unroll
            for (int i = 0; i < 16; ++i) {
                f32x4 h4 = hreg[i];
#pragma unroll
                for (int jj = 0; jj < 8; ++jj) {
                    f32x4 a4 = *(const f32x4*)(w2 + ((size_t)jj << 10) + (i << 2));
                    acc[jj] += h4.x * a4.x + h4.y * a4.y + h4.z * a4.z + h4.w * a4.w;
                    f32x4 b4 = *(const f32x4*)(wqb + ((size_t)jj << 10) + (i << 2));
                    acc[8 + jj] += h4.x * b4.x + h4.y * b4.y + h4.z * b4.z + h4.w * b4.w;
                }
            }
#pragma unroll
            for (int u = 0; u < 16; ++u) red[u][ks][b] = acc[u];
            __syncthreads();
            if (tid < 256) {
                const int fj = tid >> 5, fb = tid & 31, j = j0 + fj;
                float sn = 0.f, sq = 0.f;
#pragma unroll
                for (int q = 0; q < 16; ++q) {
                    sn += red[fj][q][fb];
                    sq += red[8 + fj][q][fb];
                }
                shs[2][fj][fb] = sn;
                cstore(qroll + ((size_t)t * BB + fb) * HH + j, sq + bq[j]);
            }
        }
        gbar(bar, NBD / 8, bstep);
        // ===== P2: attention blocks =====
        if (!isg) {
            if (tid < 256) {
                f32x4 qv = ntld4(qroll + ((size_t)t * BB + ab) * HH + tid * 4);
                *(f32x4*)&qs[tid * 4] = qv;
            }
            __syncthreads();
            {
                const int s4 = tid >> 3, kq = tid & 7;
                const float* kr = keys + (size_t)(ab * SS + s4) * HH + kq * 128;
                float a = 0.f;
                for (int i = 0; i < 32; ++i) {
                    f32x4 kv = ntld4(kr + (i << 2));
                    int k = kq * 128 + (i << 2);
                    a += tanh_f(qs[k] + kv.x) * wss[k]
                       + tanh_f(qs[k + 1] + kv.y) * wss[k + 1]
                       + tanh_f(qs[k + 2] + kv.z) * wss[k + 2]
                       + tanh_f(qs[k + 3] + kv.w) * wss[k + 3];
                }
                sc[kq][s4] = a;
            }
            __syncthreads();
            if (tid < 64) {
                float v = bsv[0];
#pragma unroll
                for (int q = 0; q < 8; ++q) v += sc[q][tid];
                bool valid = src[ab * SS + tid] != 0;
                float m = valid ? v : -3.0e38f;
                for (int off = 32; off; off >>= 1) m = fmaxf(m, __shfl_xor(m, off));
                float e = valid ? __expf(v - m) : 0.f;
                float ssum = e;
                for (int off = 32; off; off >>= 1) ssum += __shfl_xor(ssum, off);
                float wgt = e / ssum;
                wl[tid] = wgt;
                attn_out[((size_t)ab * TD + t) * SS + tid] = wgt;
            }
            __syncthreads();
            if (tid < 256) {
                f32x4 a4 = {0.f, 0.f, 0.f, 0.f};
                const float* er = enc_out + (size_t)ab * SS * HH + tid * 4;
                for (int s2 = 0; s2 < SS; ++s2) {
                    float wgt = wl[s2];
                    f32x4 ev = ntld4(er + ((size_t)s2 << 10));
                    a4.x += wgt * ev.x; a4.y += wgt * ev.y;
                    a4.z += wgt * ev.z; a4.w += wgt * ev.w;
                }
                float* cp = ctxroll + ((size_t)t * BB + ab) * HH + tid * 4;
                cstore(cp + 0, a4.x);
                cstore(cp + 1, a4.y);
                cstore(cp + 2, a4.z);
                cstore(cp + 3, a4.w);
            }
        }
        gbar(bar, NBD / 8, bstep);
        // ===== P3: GRU blocks: ctx-side dots + finalize =====
        if (isg) {
            f32x4 creg[16];
            const float* cb = ctxroll + ((size_t)t * BB + b) * HH + kc;
#pragma unroll
            for (int i = 0; i < 16; ++i) creg[i] = ntld4(cb + (i << 2));
            float acc[24];
#pragma unroll
            for (int u = 0; u < 24; ++u) acc[u] = 0.f;
#pragma unroll
            for (int i = 0; i < 16; ++i) {
                f32x4 c4 = creg[i];
#pragma unroll
                for (int jj = 0; jj < 8; ++jj) {
                    f32x4 a4 = *(const f32x4*)(x0 + (size_t)jj * (EE + HH) + (i << 2));
                    acc[jj] += c4.x * a4.x + c4.y * a4.y + c4.z * a4.z + c4.w * a4.w;
                    f32x4 b4 = *(const f32x4*)(x1 + (size_t)jj * (EE + HH) + (i << 2));
                    acc[8 + jj] += c4.x * b4.x + c4.y * b4.y + c4.z * b4.z + c4.w * b4.w;
                    f32x4 d4 = *(const f32x4*)(x2 + (size_t)jj * (EE + HH) + (i << 2));
                    acc[16 + jj] += c4.x * d4.x + c4.y * d4.y + c4.z * d4.z + c4.w * d4.w;
                }
            }
#pragma unroll
            for (int u = 0; u < 24; ++u) red[u][ks][b] = acc[u];
            __syncthreads();
            if (tid < 256) {
                const int fj = tid >> 5, fb = tid & 31, j = j0 + fj;
                float sx0 = 0.f, sx1 = 0.f, sx2 = 0.f;
#pragma unroll
                for (int q = 0; q < 16; ++q) {
                    sx0 += red[fj][q][fb];
                    sx1 += red[8 + fj][q][fb];
                    sx2 += red[16 + fj][q][fb];
                }
                const float* gr = gi + (size_t)(t * BB + fb) * GG;
                float g0 = __builtin_nontemporal_load(gr + j);
                float g1 = __builtin_nontemporal_load(gr + HH + j);
                float g2 = __builtin_nontemporal_load(gr + 2 * HH + j);
                float r = sigmoid_f(g0 + sx0 + shs[0][fj][fb] + bhh[j]);
                float z = sigmoid_f(g1 + sx1 + shs[1][fj][fb] + bhh[HH + j]);
                float n = tanh_f(g2 + sx2 + r * (shs[2][fj][fb] + bhh[2 * HH + j]));
                float hold = (t == 0)
                    ? __builtin_nontemporal_load(enc_out + ((size_t)fb * SS + (SS - 1)) * HH + j)
                    : __builtin_nontemporal_load(h2all + ((size_t)(t - 1) * BB + fb) * HH + j);
                float hnew = (1.f - z) * n + z * hold;
                cstore(h2all + ((size_t)t * BB + fb) * HH + j, hnew);
            }
        }
        gbar(bar, NBD / 8, bstep);
    }
}

extern "C" void kernel_launch(void* const* d_in, const int* in_sizes, int n_in,
                              void* d_out, int out_size, void* d_ws, size_t ws_size,
                              hipStream_t stream)
{
    const int*   src  = (const int*)d_in[0];
    const int*   tgt  = (const int*)d_in[1];
    const float* eemb = (const float*)d_in[2];
    const float* ewih = (const float*)d_in[3];
    const float* ewhh = (const float*)d_in[4];
    const float* ebih = (const float*)d_in[5];
    const float* ebhh = (const float*)d_in[6];
    const float* wq   = (const float*)d_in[7];
    const float* bq   = (const float*)d_in[8];
    const float* wk   = (const float*)d_in[9];
    const float* bk   = (const float*)d_in[10];
    const float* wsv  = (const float*)d_in[11];
    const float* bsv  = (const float*)d_in[12];
    const float* demb = (const float*)d_in[13];
    const float* dwih = (const float*)d_in[14];
    const float* dwhh = (const float*)d_in[15];
    const float* dbih = (const float*)d_in[16];
    const float* dbhh = (const float*)d_in[17];
    const float* wo   = (const float*)d_in[18];
    const float* bo   = (const float*)d_in[19];
    float* out = (float*)d_out;

    float* w = (float*)d_ws;
    float* enc_gi  = w;                                 // [B*S][3H]
    float* dec_gi  = enc_gi  + (size_t)BB * SS * GG;    // [TD*B][3H]
    float* enc_out = dec_gi  + (size_t)TD * BB * GG;    // [B][S][H] (enc h rotation)
    float* keys    = enc_out + (size_t)BB * SS * HH;    // [B*S][H]
    float* h2all   = keys    + (size_t)BB * SS * HH;    // [TD][B][H] (dec h rotation)
    float* qroll   = h2all   + (size_t)TD * BB * HH;    // [TD][B][H]
    float* ctxroll = qroll   + (size_t)TD * BB * HH;    // [TD][B][H]
    int*   didx    = (int*)(ctxroll + (size_t)TD * BB * HH); // [TD*B]
    int*   barE    = didx + TD * BB + 64;
    int*   barD    = barE + 1024;

    float* attn_out = out + (size_t)BB * TD * VV;

    hipMemsetAsync(barE, 0, 2048 * sizeof(int), stream);
    k_dec_idx<<<dim3((TD * BB + 255) / 256), 256, 0, stream>>>(tgt, didx);

    // enc_gi = gather(enc_embed)@enc_w_ih^T + b_ih
    k_gemm<<<dim3(GG / 64, (BB * SS) / 64), 256, 0, stream>>>(
        eemb, ewih, ebih, enc_gi, src, BB * SS, GG, EE, EE, EE, GG, 0);
    // dec_gi = gather(dec_embed)@dec_w_ih[:, :E]^T + b_ih
    k_gemm<<<dim3(GG / 64, (TD * BB + 63) / 64), 256, 0, stream>>>(
        demb, dwih, dbih, dec_gi, didx, TD * BB, GG, EE, EE, EE + HH, GG, 0);

    p_enc<<<dim3(NBE), dim3(NTHR), 0, stream>>>(
        enc_gi, ewhh, ebhh, enc_out, barE);

    // keys = enc_out @ wk^T + bk   (enc_out rows are [b*S+s][H] — same as before)
    k_gemm<<<dim3(HH / 64, (BB * SS) / 64), 256, 0, stream>>>(
        enc_out, wk, bk, keys, nullptr, BB * SS, HH, HH, HH, HH, HH, 0);

    p_dec<<<dim3(NBD), dim3(NTHR), 0, stream>>>(
        dec_gi, dwhh, dbhh, dwih, wq, bq, keys, wsv, bsv, src, enc_out,
        h2all, qroll, ctxroll, attn_out, barD);

    // logits = h2all @ wo^T + bo, rows permuted (t*B+b) -> (b*TD+t)
    k_gemm<<<dim3(VV / 64, (TD * BB + 63) / 64), 256, 0, stream>>>(
        h2all, wo, bo, out, nullptr, TD * BB, VV, HH, HH, HH, VV, 1);
}

// Round 7
// 14331.444 us; speedup vs baseline: 1.5387x; 1.5387x over previous
//
#include <hip/hip_runtime.h>

// Seq2Seq GRU + Bahdanau attention, fp32. B=32 S=64 T=48 E=512 H=1024 V=32000.
// R7: R6's register-lean persistent engine, but decoder grid = EXACTLY 256
// blocks (attention merged into blocks 0..31 as a second role) so all blocks
// are co-resident at 1 block/CU — fixes R6's grid-residency deadlock
// (288 blocks > 256 resident slots at 8 waves/block).

#define BB 32
#define SS 64
#define TT 48
#define TD 47
#define EE 512
#define HH 1024
#define GG 3072
#define VV 32000
#define SOS_IDX 1
#define NBE 256          // encoder blocks (4 j-cols each)
#define NBD 256          // decoder blocks (4 j-cols each; 0..31 also attention)
#define NBA 32
#define NTHR 512

typedef float f32x4 __attribute__((ext_vector_type(4)));

static __device__ __forceinline__ float sigmoid_f(float x) {
    return 1.0f / (1.0f + __expf(-x));
}
static __device__ __forceinline__ float tanh_f(float x) {
    return 1.0f - 2.0f / (__expf(2.0f * x) + 1.0f);
}
static __device__ __forceinline__ f32x4 ntld4(const float* p) {
    return __builtin_nontemporal_load((const f32x4*)p);
}
// write-through 16B store: visible at device scope once vmcnt==0.
static __device__ __forceinline__ void cst4(float* p, f32x4 v) {
    asm volatile("global_store_dwordx4 %0, %1, off sc0 sc1" :: "v"(p), "v"(v) : "memory");
}

// Two-level monotonic grid barrier (8 leaves + root), fence-free.
static __device__ __forceinline__ void gbar(int* bar, int leafsz, int& bstep) {
    asm volatile("s_waitcnt vmcnt(0) lgkmcnt(0)" ::: "memory");
    __syncthreads();
    bstep += 1;
    if (threadIdx.x == 0) {
        int* leaf = bar + (blockIdx.x & 7) * 32;
        int* root = bar + 512;
        int lv = __hip_atomic_fetch_add(leaf, 1, __ATOMIC_RELAXED, __HIP_MEMORY_SCOPE_AGENT) + 1;
        if (lv == bstep * leafsz) {
            __hip_atomic_fetch_add(root, 1, __ATOMIC_RELAXED, __HIP_MEMORY_SCOPE_AGENT);
        }
        while (__hip_atomic_load(root, __ATOMIC_RELAXED, __HIP_MEMORY_SCOPE_AGENT) < bstep * 8) {
            __builtin_amdgcn_s_sleep(1);
        }
    }
    __syncthreads();
    asm volatile("" ::: "memory");
}

__global__ void k_dec_idx(const int* __restrict__ tgt, int* __restrict__ idx) {
    int m = blockIdx.x * 256 + threadIdx.x;
    if (m < TD * BB) {
        int t = m >> 5, b = m & 31;
        idx[m] = (t == 0) ? SOS_IDX : tgt[b * TT + t];
    }
}

// C[m,n] = sum_k A[row(m),k] * Wt[n,k] + bias[n]
__global__ __launch_bounds__(256) void k_gemm(
    const float* __restrict__ A, const float* __restrict__ Wt,
    const float* __restrict__ bias, float* __restrict__ C,
    const int* __restrict__ rowidx,
    int M, int N, int K, int lda, int ldw, int ldc, int permute)
{
    __shared__ __align__(16) float As[16][64];
    __shared__ __align__(16) float Bs[16][64];
    const int tid = threadIdx.x;
    const int tm = tid >> 4;
    const int tn = tid & 15;
    const int row0 = blockIdx.y * 64;
    const int col0 = blockIdx.x * 64;
    const int lr = tid >> 2;
    const int lq = tid & 3;

    long arow_off = -1;
    {
        int arow = row0 + lr;
        if (arow < M) {
            int r = rowidx ? rowidx[arow] : arow;
            arow_off = (long)r * lda;
        }
    }
    long wrow_off = -1;
    {
        int wcol = col0 + lr;
        if (wcol < N) wrow_off = (long)wcol * ldw;
    }

    float acc[4][4];
#pragma unroll
    for (int i = 0; i < 4; ++i)
#pragma unroll
        for (int j = 0; j < 4; ++j) acc[i][j] = 0.f;

    for (int k0 = 0; k0 < K; k0 += 16) {
        float4 av = make_float4(0.f, 0.f, 0.f, 0.f);
        if (arow_off >= 0) av = *(const float4*)(A + arow_off + k0 + lq * 4);
        float4 wv = make_float4(0.f, 0.f, 0.f, 0.f);
        if (wrow_off >= 0) wv = *(const float4*)(Wt + wrow_off + k0 + lq * 4);
        __syncthreads();
        As[lq * 4 + 0][lr] = av.x; As[lq * 4 + 1][lr] = av.y;
        As[lq * 4 + 2][lr] = av.z; As[lq * 4 + 3][lr] = av.w;
        Bs[lq * 4 + 0][lr] = wv.x; Bs[lq * 4 + 1][lr] = wv.y;
        Bs[lq * 4 + 2][lr] = wv.z; Bs[lq * 4 + 3][lr] = wv.w;
        __syncthreads();
#pragma unroll
        for (int kk = 0; kk < 16; ++kk) {
            float4 a4 = *(const float4*)&As[kk][tm * 4];
            float4 b4 = *(const float4*)&Bs[kk][tn * 4];
            acc[0][0] += a4.x * b4.x; acc[0][1] += a4.x * b4.y;
            acc[0][2] += a4.x * b4.z; acc[0][3] += a4.x * b4.w;
            acc[1][0] += a4.y * b4.x; acc[1][1] += a4.y * b4.y;
            acc[1][2] += a4.y * b4.z; acc[1][3] += a4.y * b4.w;
            acc[2][0] += a4.z * b4.x; acc[2][1] += a4.z * b4.y;
            acc[2][2] += a4.z * b4.z; acc[2][3] += a4.z * b4.w;
            acc[3][0] += a4.w * b4.x; acc[3][1] += a4.w * b4.y;
            acc[3][2] += a4.w * b4.z; acc[3][3] += a4.w * b4.w;
        }
    }

    float4 bv = make_float4(0.f, 0.f, 0.f, 0.f);
    if (bias) bv = *(const float4*)(bias + col0 + tn * 4);
#pragma unroll
    for (int i = 0; i < 4; ++i) {
        int m = row0 + tm * 4 + i;
        if (m >= M) continue;
        int orow = permute ? ((m & 31) * TD + (m >> 5)) : m;
        float4 v;
        v.x = acc[i][0] + bv.x; v.y = acc[i][1] + bv.y;
        v.z = acc[i][2] + bv.z; v.w = acc[i][3] + bv.w;
        *(float4*)(C + (long)orow * ldc + col0 + tn * 4) = v;
    }
}

// ---------------- persistent encoder ----------------
// Rotation: h after step s lives at enc_out[b][s][:]. Block owns 4 j-cols.
__global__ __launch_bounds__(NTHR, 2) void p_enc(
    const float* __restrict__ gi, const float* __restrict__ Whh,
    const float* __restrict__ bhh, float* __restrict__ enc_out, int* bar)
{
    __shared__ float red[12][16][32];
    __shared__ float sums[12][32];
    const int tid = threadIdx.x, bid = blockIdx.x;
    const int b = tid & 31, ks = tid >> 5;
    const int j0 = bid * 4;
    const int kc = ks * 64;
    int bstep = 0;

    const f32x4 bh0 = *(const f32x4*)(bhh + j0);
    const f32x4 bh1 = *(const f32x4*)(bhh + HH + j0);
    const f32x4 bh2 = *(const f32x4*)(bhh + 2 * HH + j0);

    for (int s = 0; s < SS; ++s) {
        float acc[12];
#pragma unroll
        for (int u = 0; u < 12; ++u) acc[u] = 0.f;
        if (s > 0) {
            f32x4 hreg[16];
            const float* hb = enc_out + ((size_t)b * SS + (s - 1)) * HH + kc;
#pragma unroll
            for (int i = 0; i < 16; ++i) hreg[i] = *(const f32x4*)(hb + (i << 2));
#pragma unroll
            for (int jj = 0; jj < 4; ++jj) {
                const float* pr = Whh + ((size_t)(j0 + jj) << 10) + kc;
                const float* pz = Whh + ((size_t)(HH + j0 + jj) << 10) + kc;
                const float* pn = Whh + ((size_t)(2 * HH + j0 + jj) << 10) + kc;
                float ar = 0.f, az = 0.f, an = 0.f;
#pragma unroll
                for (int i = 0; i < 16; ++i) {
                    f32x4 h4 = hreg[i];
                    f32x4 w;
                    w = *(const f32x4*)(pr + (i << 2));
                    ar += h4.x * w.x + h4.y * w.y + h4.z * w.z + h4.w * w.w;
                    w = *(const f32x4*)(pz + (i << 2));
                    az += h4.x * w.x + h4.y * w.y + h4.z * w.z + h4.w * w.w;
                    w = *(const f32x4*)(pn + (i << 2));
                    an += h4.x * w.x + h4.y * w.y + h4.z * w.z + h4.w * w.w;
                }
                acc[jj] = ar; acc[4 + jj] = az; acc[8 + jj] = an;
            }
        }
#pragma unroll
        for (int u = 0; u < 12; ++u) red[u][ks][b] = acc[u];
        __syncthreads();
        if (tid < 384) {
            int u = tid >> 5, fb = tid & 31;
            float x = 0.f;
#pragma unroll
            for (int q = 0; q < 16; ++q) x += red[u][q][fb];
            sums[u][fb] = x;
        }
        __syncthreads();
        if (tid < 32) {
            const float* gr = gi + (size_t)(tid * SS + s) * GG;
            f32x4 g0 = ntld4(gr + j0);
            f32x4 g1 = ntld4(gr + HH + j0);
            f32x4 g2 = ntld4(gr + 2 * HH + j0);
            f32x4 hold = {0.f, 0.f, 0.f, 0.f};
            if (s > 0) hold = *(const f32x4*)(enc_out + ((size_t)tid * SS + (s - 1)) * HH + j0);
            f32x4 hn;
#pragma unroll
            for (int e = 0; e < 4; ++e) {
                float r = sigmoid_f(g0[e] + sums[e][tid] + bh0[e]);
                float z = sigmoid_f(g1[e] + sums[4 + e][tid] + bh1[e]);
                float n = tanh_f(g2[e] + r * (sums[8 + e][tid] + bh2[e]));
                hn[e] = (1.f - z) * n + z * hold[e];
            }
            cst4(enc_out + ((size_t)tid * SS + s) * HH + j0, hn);
        }
        gbar(bar, NBE / 8, bstep);
    }
}

// ---------------- persistent decoder ----------------
// 256 blocks. All: GRU role (4 j-cols). Blocks 0..31 additionally: attention
// for batch b=bid during P2 (others wait at the barrier).
__global__ __launch_bounds__(NTHR, 2) void p_dec(
    const float* __restrict__ gi, const float* __restrict__ Whh,
    const float* __restrict__ bhh, const float* __restrict__ Wih,
    const float* __restrict__ wq, const float* __restrict__ bq,
    const float* __restrict__ keys, const float* __restrict__ wsv,
    const float* __restrict__ bsv, const int* __restrict__ src,
    const float* __restrict__ enc_out, float* __restrict__ h2all,
    float* __restrict__ qroll, float* __restrict__ ctxroll,
    float* __restrict__ attn_out, int* bar)
{
    __shared__ float red[16][16][32];    // 32 KB
    __shared__ float shs[12][32];        // h-side gate sums (persist P1->P3)
    __shared__ float sxs[12][32];        // ctx-side gate sums
    __shared__ float qsum[4][32];
    __shared__ float qs[HH];
    __shared__ float wss[HH];
    __shared__ float sc[8][64];
    __shared__ float wl[64];
    const int tid = threadIdx.x, bid = blockIdx.x;
    const bool isa = bid < NBA;          // attention role (second duty)
    int bstep = 0;

    const int b = tid & 31, ks = tid >> 5;
    const int kc = ks * 64;
    const int j0 = bid * 4;
    const int ab = bid;

    const f32x4 bh0 = *(const f32x4*)(bhh + j0);
    const f32x4 bh1 = *(const f32x4*)(bhh + HH + j0);
    const f32x4 bh2 = *(const f32x4*)(bhh + 2 * HH + j0);
    const f32x4 bq4 = *(const f32x4*)(bq + j0);
    if (isa) {
        for (int i = tid; i < HH; i += NTHR) wss[i] = wsv[i];
    }

    for (int t = 0; t < TD; ++t) {
        // ===== P1: h-side dots for r,z,n,q (all blocks) =====
        {
            f32x4 hreg[16];
            const float* hb = (t == 0)
                ? enc_out + ((size_t)b * SS + (SS - 1)) * HH + kc
                : h2all + ((size_t)((t - 1) * BB + b)) * HH + kc;
#pragma unroll
            for (int i = 0; i < 16; ++i) hreg[i] = *(const f32x4*)(hb + (i << 2));
            float acc[16];
#pragma unroll
            for (int jj = 0; jj < 4; ++jj) {
                const float* pr = Whh + ((size_t)(j0 + jj) << 10) + kc;
                const float* pz = Whh + ((size_t)(HH + j0 + jj) << 10) + kc;
                const float* pn = Whh + ((size_t)(2 * HH + j0 + jj) << 10) + kc;
                const float* pq = wq + ((size_t)(j0 + jj) << 10) + kc;
                float ar = 0.f, az = 0.f, an = 0.f, aq = 0.f;
#pragma unroll
                for (int i = 0; i < 16; ++i) {
                    f32x4 h4 = hreg[i];
                    f32x4 w;
                    w = *(const f32x4*)(pr + (i << 2));
                    ar += h4.x * w.x + h4.y * w.y + h4.z * w.z + h4.w * w.w;
                    w = *(const f32x4*)(pz + (i << 2));
                    az += h4.x * w.x + h4.y * w.y + h4.z * w.z + h4.w * w.w;
                    w = *(const f32x4*)(pn + (i << 2));
                    an += h4.x * w.x + h4.y * w.y + h4.z * w.z + h4.w * w.w;
                    w = *(const f32x4*)(pq + (i << 2));
                    aq += h4.x * w.x + h4.y * w.y + h4.z * w.z + h4.w * w.w;
                }
                acc[jj] = ar; acc[4 + jj] = az; acc[8 + jj] = an; acc[12 + jj] = aq;
            }
#pragma unroll
            for (int u = 0; u < 16; ++u) red[u][ks][b] = acc[u];
            __syncthreads();
            {
                int u = tid >> 5, fb = tid & 31;
                float x = 0.f;
#pragma unroll
                for (int q = 0; q < 16; ++q) x += red[u][q][fb];
                if (u < 12) shs[u][fb] = x;
                else qsum[u - 12][fb] = x;
            }
            __syncthreads();
            if (tid < 32) {
                f32x4 qv;
                qv.x = qsum[0][tid] + bq4.x;
                qv.y = qsum[1][tid] + bq4.y;
                qv.z = qsum[2][tid] + bq4.z;
                qv.w = qsum[3][tid] + bq4.w;
                cst4(qroll + ((size_t)(t * BB + tid)) * HH + j0, qv);
            }
        }
        gbar(bar, NBD / 8, bstep);
        // ===== P2: attention (blocks 0..31 only) =====
        if (isa) {
            if (tid < 256)
                *(f32x4*)&qs[tid * 4] =
                    *(const f32x4*)(qroll + ((size_t)(t * BB + ab)) * HH + tid * 4);
            __syncthreads();
            {
                const int s4 = tid >> 3, kq = tid & 7;
                const float* kr = keys + (size_t)(ab * SS + s4) * HH + kq * 128;
                float a = 0.f;
                for (int i = 0; i < 32; ++i) {
                    f32x4 kv = ntld4(kr + (i << 2));
                    int k = kq * 128 + (i << 2);
                    a += tanh_f(qs[k] + kv.x) * wss[k]
                       + tanh_f(qs[k + 1] + kv.y) * wss[k + 1]
                       + tanh_f(qs[k + 2] + kv.z) * wss[k + 2]
                       + tanh_f(qs[k + 3] + kv.w) * wss[k + 3];
                }
                sc[kq][s4] = a;
            }
            __syncthreads();
            if (tid < 64) {
                float v = bsv[0];
#pragma unroll
                for (int q = 0; q < 8; ++q) v += sc[q][tid];
                bool valid = src[ab * SS + tid] != 0;
                float m = valid ? v : -3.0e38f;
                for (int off = 32; off; off >>= 1) m = fmaxf(m, __shfl_xor(m, off));
                float e = valid ? __expf(v - m) : 0.f;
                float ssum = e;
                for (int off = 32; off; off >>= 1) ssum += __shfl_xor(ssum, off);
                float wgt = e / ssum;
                wl[tid] = wgt;
                __builtin_nontemporal_store(wgt, attn_out + ((size_t)ab * TD + t) * SS + tid);
            }
            __syncthreads();
            if (tid < 256) {
                f32x4 a4 = {0.f, 0.f, 0.f, 0.f};
                const float* er = enc_out + (size_t)ab * SS * HH + tid * 4;
                for (int s2 = 0; s2 < SS; ++s2) {
                    float wgt = wl[s2];
                    f32x4 ev = ntld4(er + ((size_t)s2 << 10));
                    a4.x += wgt * ev.x; a4.y += wgt * ev.y;
                    a4.z += wgt * ev.z; a4.w += wgt * ev.w;
                }
                cst4(ctxroll + ((size_t)(t * BB + ab)) * HH + tid * 4, a4);
            }
        }
        gbar(bar, NBD / 8, bstep);
        // ===== P3: ctx-side dots + finalize (all blocks) =====
        {
            f32x4 creg[16];
            const float* cb = ctxroll + ((size_t)(t * BB + b)) * HH + kc;
#pragma unroll
            for (int i = 0; i < 16; ++i) creg[i] = *(const f32x4*)(cb + (i << 2));
            float acc[12];
#pragma unroll
            for (int jj = 0; jj < 4; ++jj) {
                const float* pr = Wih + (size_t)(j0 + jj) * (EE + HH) + EE + kc;
                const float* pz = Wih + (size_t)(HH + j0 + jj) * (EE + HH) + EE + kc;
                const float* pn = Wih + (size_t)(2 * HH + j0 + jj) * (EE + HH) + EE + kc;
                float ar = 0.f, az = 0.f, an = 0.f;
#pragma unroll
                for (int i = 0; i < 16; ++i) {
                    f32x4 c4 = creg[i];
                    f32x4 w;
                    w = *(const f32x4*)(pr + (i << 2));
                    ar += c4.x * w.x + c4.y * w.y + c4.z * w.z + c4.w * w.w;
                    w = *(const f32x4*)(pz + (i << 2));
                    az += c4.x * w.x + c4.y * w.y + c4.z * w.z + c4.w * w.w;
                    w = *(const f32x4*)(pn + (i << 2));
                    an += c4.x * w.x + c4.y * w.y + c4.z * w.z + c4.w * w.w;
                }
                acc[jj] = ar; acc[4 + jj] = az; acc[8 + jj] = an;
            }
#pragma unroll
            for (int u = 0; u < 12; ++u) red[u][ks][b] = acc[u];
            __syncthreads();
            if (tid < 384) {
                int u = tid >> 5, fb = tid & 31;
                float x = 0.f;
#pragma unroll
                for (int q = 0; q < 16; ++q) x += red[u][q][fb];
                sxs[u][fb] = x;
            }
            __syncthreads();
            if (tid < 32) {
                const float* gr = gi + (size_t)(t * BB + tid) * GG;
                f32x4 g0 = ntld4(gr + j0);
                f32x4 g1 = ntld4(gr + HH + j0);
                f32x4 g2 = ntld4(gr + 2 * HH + j0);
                f32x4 hold = (t == 0)
                    ? *(const f32x4*)(enc_out + ((size_t)tid * SS + (SS - 1)) * HH + j0)
                    : *(const f32x4*)(h2all + ((size_t)((t - 1) * BB + tid)) * HH + j0);
                f32x4 hn;
#pragma unroll
                for (int e = 0; e < 4; ++e) {
                    float r = sigmoid_f(g0[e] + sxs[e][tid] + shs[e][tid] + bh0[e]);
                    float z = sigmoid_f(g1[e] + sxs[4 + e][tid] + shs[4 + e][tid] + bh1[e]);
                    float n = tanh_f(g2[e] + sxs[8 + e][tid] + r * (shs[8 + e][tid] + bh2[e]));
                    hn[e] = (1.f - z) * n + z * hold[e];
                }
                cst4(h2all + ((size_t)(t * BB + tid)) * HH + j0, hn);
            }
        }
        gbar(bar, NBD / 8, bstep);
    }
}

extern "C" void kernel_launch(void* const* d_in, const int* in_sizes, int n_in,
                              void* d_out, int out_size, void* d_ws, size_t ws_size,
                              hipStream_t stream)
{
    const int*   src  = (const int*)d_in[0];
    const int*   tgt  = (const int*)d_in[1];
    const float* eemb = (const float*)d_in[2];
    const float* ewih = (const float*)d_in[3];
    const float* ewhh = (const float*)d_in[4];
    const float* ebih = (const float*)d_in[5];
    const float* ebhh = (const float*)d_in[6];
    const float* wq   = (const float*)d_in[7];
    const float* bq   = (const float*)d_in[8];
    const float* wk   = (const float*)d_in[9];
    const float* bk   = (const float*)d_in[10];
    const float* wsv  = (const float*)d_in[11];
    const float* bsv  = (const float*)d_in[12];
    const float* demb = (const float*)d_in[13];
    const float* dwih = (const float*)d_in[14];
    const float* dwhh = (const float*)d_in[15];
    const float* dbih = (const float*)d_in[16];
    const float* dbhh = (const float*)d_in[17];
    const float* wo   = (const float*)d_in[18];
    const float* bo   = (const float*)d_in[19];
    float* out = (float*)d_out;

    float* w = (float*)d_ws;
    float* enc_gi  = w;                                 // [B*S][3H]
    float* dec_gi  = enc_gi  + (size_t)BB * SS * GG;    // [TD*B][3H]
    float* enc_out = dec_gi  + (size_t)TD * BB * GG;    // [B][S][H] (enc h rotation)
    float* keys    = enc_out + (size_t)BB * SS * HH;    // [B*S][H]
    float* h2all   = keys    + (size_t)BB * SS * HH;    // [TD][B][H] (dec h rotation)
    float* qroll   = h2all   + (size_t)TD * BB * HH;    // [TD][B][H]
    float* ctxroll = qroll   + (size_t)TD * BB * HH;    // [TD][B][H]
    int*   didx    = (int*)(ctxroll + (size_t)TD * BB * HH); // [TD*B]
    int*   barE    = didx + TD * BB + 64;
    int*   barD    = barE + 1024;

    float* attn_out = out + (size_t)BB * TD * VV;

    hipMemsetAsync(barE, 0, 2048 * sizeof(int), stream);
    k_dec_idx<<<dim3((TD * BB + 255) / 256), 256, 0, stream>>>(tgt, didx);

    // enc_gi = gather(enc_embed)@enc_w_ih^T + b_ih
    k_gemm<<<dim3(GG / 64, (BB * SS) / 64), 256, 0, stream>>>(
        eemb, ewih, ebih, enc_gi, src, BB * SS, GG, EE, EE, EE, GG, 0);
    // dec_gi = gather(dec_embed)@dec_w_ih[:, :E]^T + b_ih
    k_gemm<<<dim3(GG / 64, (TD * BB + 63) / 64), 256, 0, stream>>>(
        demb, dwih, dbih, dec_gi, didx, TD * BB, GG, EE, EE, EE + HH, GG, 0);

    p_enc<<<dim3(NBE), dim3(NTHR), 0, stream>>>(
        enc_gi, ewhh, ebhh, enc_out, barE);

    // keys = enc_out @ wk^T + bk
    k_gemm<<<dim3(HH / 64, (BB * SS) / 64), 256, 0, stream>>>(
        enc_out, wk, bk, keys, nullptr, BB * SS, HH, HH, HH, HH, HH, 0);

    p_dec<<<dim3(NBD), dim3(NTHR), 0, stream>>>(
        dec_gi, dwhh, dbhh, dwih, wq, bq, keys, wsv, bsv, src, enc_out,
        h2all, qroll, ctxroll, attn_out, barD);

    // logits = h2all @ wo^T + bo, rows permuted (t*B+b) -> (b*TD+t)
    k_gemm<<<dim3(VV / 64, (TD * BB + 63) / 64), 256, 0, stream>>>(
        h2all, wo, bo, out, nullptr, TD * BB, VV, HH, HH, HH, VV, 1);
}

// Round 8
// 5569.568 us; speedup vs baseline: 3.9594x; 2.5732x over previous
//
#include <hip/hip_runtime.h>

// Seq2Seq GRU + Bahdanau attention, fp32. B=32 S=64 T=48 E=512 H=1024 V=32000.
// R8: back to multi-launch recurrence (kernel boundaries = free coherence; the
// R1 structure that actually worked), with the register-lean 4-col/block GRU
// engine from R6/R7 and NO nt-hints on reused data. Logits GEMM upgraded to
// 128x128 tile / 8x8-per-thread (quadrant layout, 2-way-max LDS conflicts).

#define BB 32
#define SS 64
#define TT 48
#define TD 47
#define EE 512
#define HH 1024
#define GG 3072
#define VV 32000
#define SOS_IDX 1

typedef float f32x4 __attribute__((ext_vector_type(4)));

static __device__ __forceinline__ float sigmoid_f(float x) {
    return 1.0f / (1.0f + __expf(-x));
}
static __device__ __forceinline__ float tanh_f(float x) {
    return 1.0f - 2.0f / (__expf(2.0f * x) + 1.0f);
}

__global__ void k_dec_idx(const int* __restrict__ tgt, int* __restrict__ idx) {
    int m = blockIdx.x * 256 + threadIdx.x;
    if (m < TD * BB) {
        int t = m >> 5, b = m & 31;
        idx[m] = (t == 0) ? SOS_IDX : tgt[b * TT + t];
    }
}

// ---------------- 128x128-tile fp32 GEMM ----------------
// C[m,n] = sum_k A[row(m),k] * Wt[n,k] + bias[n]; row(m)=rowidx?rowidx[m]:m.
// permute=1: output row = (m&31)*TD + (m>>5). N must be divisible by 128.
// Thread (tm=tid>>4, tn=tid&15) owns rows {tm*4+i, 64+tm*4+i} x cols
// {tn*4+j, 64+tn*4+j} (quadrant layout -> 2-way max LDS bank aliasing).
__global__ __launch_bounds__(256) void k_gemm128(
    const float* __restrict__ A, const float* __restrict__ Wt,
    const float* __restrict__ bias, float* __restrict__ C,
    const int* __restrict__ rowidx,
    int M, int N, int K, int lda, int ldw, int ldc, int permute)
{
    __shared__ __align__(16) float As[16][128];
    __shared__ __align__(16) float Bs[16][128];
    const int tid = threadIdx.x;
    const int tm = tid >> 4, tn = tid & 15;
    const int row0 = blockIdx.y * 128;
    const int col0 = blockIdx.x * 128;
    const int lr = tid >> 1;        // 0..127 (A/B row within tile)
    const int lq = tid & 1;         // k-half (8 floats each)

    long arow_off = -1;
    {
        int arow = row0 + lr;
        if (arow < M) {
            int r = rowidx ? rowidx[arow] : arow;
            arow_off = (long)r * lda;
        }
    }
    const long wrow_off = (long)(col0 + lr) * ldw;

    float acc[8][8];
#pragma unroll
    for (int i = 0; i < 8; ++i)
#pragma unroll
        for (int j = 0; j < 8; ++j) acc[i][j] = 0.f;

    for (int k0 = 0; k0 < K; k0 += 16) {
        f32x4 av0 = {0.f,0.f,0.f,0.f}, av1 = {0.f,0.f,0.f,0.f};
        if (arow_off >= 0) {
            av0 = *(const f32x4*)(A + arow_off + k0 + lq * 8);
            av1 = *(const f32x4*)(A + arow_off + k0 + lq * 8 + 4);
        }
        f32x4 wv0 = *(const f32x4*)(Wt + wrow_off + k0 + lq * 8);
        f32x4 wv1 = *(const f32x4*)(Wt + wrow_off + k0 + lq * 8 + 4);
        __syncthreads();
#pragma unroll
        for (int i = 0; i < 4; ++i) {
            As[lq * 8 + i][lr] = av0[i];
            As[lq * 8 + 4 + i][lr] = av1[i];
            Bs[lq * 8 + i][lr] = wv0[i];
            Bs[lq * 8 + 4 + i][lr] = wv1[i];
        }
        __syncthreads();
#pragma unroll
        for (int kk = 0; kk < 16; ++kk) {
            f32x4 a0 = *(const f32x4*)&As[kk][tm * 4];
            f32x4 a1 = *(const f32x4*)&As[kk][64 + tm * 4];
            f32x4 b0 = *(const f32x4*)&Bs[kk][tn * 4];
            f32x4 b1 = *(const f32x4*)&Bs[kk][64 + tn * 4];
            float a[8], b[8];
#pragma unroll
            for (int i = 0; i < 4; ++i) {
                a[i] = a0[i]; a[4 + i] = a1[i];
                b[i] = b0[i]; b[4 + i] = b1[i];
            }
#pragma unroll
            for (int i = 0; i < 8; ++i)
#pragma unroll
                for (int j = 0; j < 8; ++j) acc[i][j] += a[i] * b[j];
        }
    }

    f32x4 bv0 = {0.f,0.f,0.f,0.f}, bv1 = {0.f,0.f,0.f,0.f};
    if (bias) {
        bv0 = *(const f32x4*)(bias + col0 + tn * 4);
        bv1 = *(const f32x4*)(bias + col0 + 64 + tn * 4);
    }
#pragma unroll
    for (int i = 0; i < 8; ++i) {
        int m = row0 + ((i < 4) ? (tm * 4 + i) : (64 + tm * 4 + i - 4));
        if (m >= M) continue;
        int orow = permute ? ((m & 31) * TD + (m >> 5)) : m;
        f32x4 v0, v1;
#pragma unroll
        for (int j = 0; j < 4; ++j) {
            v0[j] = acc[i][j] + bv0[j];
            v1[j] = acc[i][4 + j] + bv1[j];
        }
        *(f32x4*)(C + (long)orow * ldc + col0 + tn * 4) = v0;
        *(f32x4*)(C + (long)orow * ldc + col0 + 64 + tn * 4) = v1;
    }
}

// ---------------- encoder step (one launch per s) ----------------
// 256 blocks x 512 thr; block owns 4 j-cols. Thread=(b=tid&31, ks=tid>>5).
// h after step s lives at enc_out[b][s][:]. s==0 reads nothing (h=0).
__global__ __launch_bounds__(512, 2) void k_enc_step(
    const float* __restrict__ gi, const float* __restrict__ Whh,
    const float* __restrict__ bhh, float* __restrict__ enc_out, int s)
{
    __shared__ float red[12][16][32];
    __shared__ float sums[12][32];
    const int tid = threadIdx.x, bid = blockIdx.x;
    const int b = tid & 31, ks = tid >> 5;
    const int j0 = bid * 4;
    const int kc = ks * 64;

    float acc[12];
#pragma unroll
    for (int u = 0; u < 12; ++u) acc[u] = 0.f;
    if (s > 0) {
        f32x4 hreg[16];
        const float* hb = enc_out + ((size_t)b * SS + (s - 1)) * HH + kc;
#pragma unroll
        for (int i = 0; i < 16; ++i) hreg[i] = *(const f32x4*)(hb + (i << 2));
#pragma unroll
        for (int jj = 0; jj < 4; ++jj) {
            const float* pr = Whh + ((size_t)(j0 + jj) << 10) + kc;
            const float* pz = Whh + ((size_t)(HH + j0 + jj) << 10) + kc;
            const float* pn = Whh + ((size_t)(2 * HH + j0 + jj) << 10) + kc;
            float ar = 0.f, az = 0.f, an = 0.f;
#pragma unroll
            for (int i = 0; i < 16; ++i) {
                f32x4 h4 = hreg[i];
                f32x4 w;
                w = *(const f32x4*)(pr + (i << 2));
                ar += h4.x * w.x + h4.y * w.y + h4.z * w.z + h4.w * w.w;
                w = *(const f32x4*)(pz + (i << 2));
                az += h4.x * w.x + h4.y * w.y + h4.z * w.z + h4.w * w.w;
                w = *(const f32x4*)(pn + (i << 2));
                an += h4.x * w.x + h4.y * w.y + h4.z * w.z + h4.w * w.w;
            }
            acc[jj] = ar; acc[4 + jj] = az; acc[8 + jj] = an;
        }
    }
#pragma unroll
    for (int u = 0; u < 12; ++u) red[u][ks][b] = acc[u];
    __syncthreads();
    if (tid < 384) {
        int u = tid >> 5, fb = tid & 31;
        float x = 0.f;
#pragma unroll
        for (int q = 0; q < 16; ++q) x += red[u][q][fb];
        sums[u][fb] = x;
    }
    __syncthreads();
    if (tid < 32) {
        const f32x4 bh0 = *(const f32x4*)(bhh + j0);
        const f32x4 bh1 = *(const f32x4*)(bhh + HH + j0);
        const f32x4 bh2 = *(const f32x4*)(bhh + 2 * HH + j0);
        const float* gr = gi + (size_t)(tid * SS + s) * GG;
        f32x4 g0 = *(const f32x4*)(gr + j0);
        f32x4 g1 = *(const f32x4*)(gr + HH + j0);
        f32x4 g2 = *(const f32x4*)(gr + 2 * HH + j0);
        f32x4 hold = {0.f, 0.f, 0.f, 0.f};
        if (s > 0) hold = *(const f32x4*)(enc_out + ((size_t)tid * SS + (s - 1)) * HH + j0);
        f32x4 hn;
#pragma unroll
        for (int e = 0; e < 4; ++e) {
            float r = sigmoid_f(g0[e] + sums[e][tid] + bh0[e]);
            float z = sigmoid_f(g1[e] + sums[4 + e][tid] + bh1[e]);
            float n = tanh_f(g2[e] + r * (sums[8 + e][tid] + bh2[e]));
            hn[e] = (1.f - z) * n + z * hold[e];
        }
        *(f32x4*)(enc_out + ((size_t)tid * SS + s) * HH + j0) = hn;
    }
}

// ---------------- decoder step kernel A: h-side dots + q ----------------
// 256 blocks x 512 thr. hbase/hstride locate h_t rows per batch.
// Writes qbuf[b][j0..3] and hsums[bid][12][32].
__global__ __launch_bounds__(512, 2) void k_hq(
    const float* __restrict__ hbase, long hstride,
    const float* __restrict__ Whh, const float* __restrict__ wq,
    const float* __restrict__ bq, float* __restrict__ qbuf,
    float* __restrict__ hsums)
{
    __shared__ float red[16][16][32];
    __shared__ float qsum[4][32];
    const int tid = threadIdx.x, bid = blockIdx.x;
    const int b = tid & 31, ks = tid >> 5;
    const int j0 = bid * 4;
    const int kc = ks * 64;

    f32x4 hreg[16];
    const float* hb = hbase + (size_t)b * hstride + kc;
#pragma unroll
    for (int i = 0; i < 16; ++i) hreg[i] = *(const f32x4*)(hb + (i << 2));
    float acc[16];
#pragma unroll
    for (int jj = 0; jj < 4; ++jj) {
        const float* pr = Whh + ((size_t)(j0 + jj) << 10) + kc;
        const float* pz = Whh + ((size_t)(HH + j0 + jj) << 10) + kc;
        const float* pn = Whh + ((size_t)(2 * HH + j0 + jj) << 10) + kc;
        const float* pq = wq + ((size_t)(j0 + jj) << 10) + kc;
        float ar = 0.f, az = 0.f, an = 0.f, aq = 0.f;
#pragma unroll
        for (int i = 0; i < 16; ++i) {
            f32x4 h4 = hreg[i];
            f32x4 w;
            w = *(const f32x4*)(pr + (i << 2));
            ar += h4.x * w.x + h4.y * w.y + h4.z * w.z + h4.w * w.w;
            w = *(const f32x4*)(pz + (i << 2));
            az += h4.x * w.x + h4.y * w.y + h4.z * w.z + h4.w * w.w;
            w = *(const f32x4*)(pn + (i << 2));
            an += h4.x * w.x + h4.y * w.y + h4.z * w.z + h4.w * w.w;
            w = *(const f32x4*)(pq + (i << 2));
            aq += h4.x * w.x + h4.y * w.y + h4.z * w.z + h4.w * w.w;
        }
        acc[jj] = ar; acc[4 + jj] = az; acc[8 + jj] = an; acc[12 + jj] = aq;
    }
#pragma unroll
    for (int u = 0; u < 16; ++u) red[u][ks][b] = acc[u];
    __syncthreads();
    {
        int u = tid >> 5, fb = tid & 31;
        float x = 0.f;
#pragma unroll
        for (int q = 0; q < 16; ++q) x += red[u][q][fb];
        if (u < 12) hsums[(size_t)bid * 384 + u * 32 + fb] = x;
        else qsum[u - 12][fb] = x;
    }
    __syncthreads();
    if (tid < 32) {
        const f32x4 bq4 = *(const f32x4*)(bq + j0);
        f32x4 qv;
        qv.x = qsum[0][tid] + bq4.x;
        qv.y = qsum[1][tid] + bq4.y;
        qv.z = qsum[2][tid] + bq4.z;
        qv.w = qsum[3][tid] + bq4.w;
        *(f32x4*)(qbuf + (size_t)tid * HH + j0) = qv;
    }
}

// ---------------- decoder step kernel B: attention ----------------
// 32 blocks (batch each) x 512 thr. Plain cached loads (keys/enc_out reused
// across all 47 steps -> want L2 residency).
__global__ __launch_bounds__(512, 2) void k_attn(
    const float* __restrict__ qbuf, const float* __restrict__ keys,
    const float* __restrict__ wsv, const float* __restrict__ bsv,
    const int* __restrict__ src, const float* __restrict__ enc_out,
    float* __restrict__ ctxbuf, float* __restrict__ attn_out, int t)
{
    __shared__ float qs[HH];
    __shared__ float wss[HH];
    __shared__ float sc[8][64];
    __shared__ float wl[64];
    const int ab = blockIdx.x;
    const int tid = threadIdx.x;
    if (tid < 256) {
        *(f32x4*)&qs[tid * 4] = *(const f32x4*)(qbuf + (size_t)ab * HH + tid * 4);
        *(f32x4*)&wss[tid * 4] = *(const f32x4*)(wsv + tid * 4);
    }
    __syncthreads();
    {
        const int s4 = tid >> 3, kq = tid & 7;
        const float* kr = keys + (size_t)(ab * SS + s4) * HH + kq * 128;
        float a = 0.f;
        for (int i = 0; i < 32; ++i) {
            f32x4 kv = *(const f32x4*)(kr + (i << 2));
            int k = kq * 128 + (i << 2);
            a += tanh_f(qs[k] + kv.x) * wss[k]
               + tanh_f(qs[k + 1] + kv.y) * wss[k + 1]
               + tanh_f(qs[k + 2] + kv.z) * wss[k + 2]
               + tanh_f(qs[k + 3] + kv.w) * wss[k + 3];
        }
        sc[kq][s4] = a;
    }
    __syncthreads();
    if (tid < 64) {
        float v = bsv[0];
#pragma unroll
        for (int q = 0; q < 8; ++q) v += sc[q][tid];
        bool valid = src[ab * SS + tid] != 0;
        float m = valid ? v : -3.0e38f;
        for (int off = 32; off; off >>= 1) m = fmaxf(m, __shfl_xor(m, off));
        float e = valid ? __expf(v - m) : 0.f;
        float ssum = e;
        for (int off = 32; off; off >>= 1) ssum += __shfl_xor(ssum, off);
        float wgt = e / ssum;
        wl[tid] = wgt;
        attn_out[((size_t)ab * TD + t) * SS + tid] = wgt;
    }
    __syncthreads();
    if (tid < 256) {
        f32x4 a4 = {0.f, 0.f, 0.f, 0.f};
        const float* er = enc_out + (size_t)ab * SS * HH + tid * 4;
        for (int s2 = 0; s2 < SS; ++s2) {
            float wgt = wl[s2];
            f32x4 ev = *(const f32x4*)(er + ((size_t)s2 << 10));
            a4.x += wgt * ev.x; a4.y += wgt * ev.y;
            a4.z += wgt * ev.z; a4.w += wgt * ev.w;
        }
        *(f32x4*)(ctxbuf + (size_t)ab * HH + tid * 4) = a4;
    }
}

// ---------------- decoder step kernel C: ctx dots + finalize ----------------
// 256 blocks x 512 thr. Reads hsums[bid], ctxbuf, gi row, hold slice; writes
// h2all[t][b][j0..3].
__global__ __launch_bounds__(512, 2) void k_fin(
    const float* __restrict__ gi, const float* __restrict__ Wih,
    const float* __restrict__ bhh, const float* __restrict__ ctxbuf,
    const float* __restrict__ hsums, const float* __restrict__ hbase,
    long hstride, float* __restrict__ h2all, int t)
{
    __shared__ float red[12][16][32];
    __shared__ float sxs[12][32];
    __shared__ float shs[12][32];
    const int tid = threadIdx.x, bid = blockIdx.x;
    const int b = tid & 31, ks = tid >> 5;
    const int j0 = bid * 4;
    const int kc = ks * 64;

    if (tid < 384) {
        int u = tid >> 5, fb = tid & 31;
        shs[u][fb] = hsums[(size_t)bid * 384 + u * 32 + fb];
    }

    f32x4 creg[16];
    const float* cb = ctxbuf + (size_t)b * HH + kc;
#pragma unroll
    for (int i = 0; i < 16; ++i) creg[i] = *(const f32x4*)(cb + (i << 2));
    float acc[12];
#pragma unroll
    for (int jj = 0; jj < 4; ++jj) {
        const float* pr = Wih + (size_t)(j0 + jj) * (EE + HH) + EE + kc;
        const float* pz = Wih + (size_t)(HH + j0 + jj) * (EE + HH) + EE + kc;
        const float* pn = Wih + (size_t)(2 * HH + j0 + jj) * (EE + HH) + EE + kc;
        float ar = 0.f, az = 0.f, an = 0.f;
#pragma unroll
        for (int i = 0; i < 16; ++i) {
            f32x4 c4 = creg[i];
            f32x4 w;
            w = *(const f32x4*)(pr + (i << 2));
            ar += c4.x * w.x + c4.y * w.y + c4.z * w.z + c4.w * w.w;
            w = *(const f32x4*)(pz + (i << 2));
            az += c4.x * w.x + c4.y * w.y + c4.z * w.z + c4.w * w.w;
            w = *(const f32x4*)(pn + (i << 2));
            an += c4.x * w.x + c4.y * w.y + c4.z * w.z + c4.w * w.w;
        }
        acc[jj] = ar; acc[4 + jj] = az; acc[8 + jj] = an;
    }
#pragma unroll
    for (int u = 0; u < 12; ++u) red[u][ks][b] = acc[u];
    __syncthreads();
    if (tid < 384) {
        int u = tid >> 5, fb = tid & 31;
        float x = 0.f;
#pragma unroll
        for (int q = 0; q < 16; ++q) x += red[u][q][fb];
        sxs[u][fb] = x;
    }
    __syncthreads();
    if (tid < 32) {
        const f32x4 bh0 = *(const f32x4*)(bhh + j0);
        const f32x4 bh1 = *(const f32x4*)(bhh + HH + j0);
        const f32x4 bh2 = *(const f32x4*)(bhh + 2 * HH + j0);
        const float* gr = gi + (size_t)(t * BB + tid) * GG;
        f32x4 g0 = *(const f32x4*)(gr + j0);
        f32x4 g1 = *(const f32x4*)(gr + HH + j0);
        f32x4 g2 = *(const f32x4*)(gr + 2 * HH + j0);
        f32x4 hold = *(const f32x4*)(hbase + (size_t)tid * hstride + j0);
        f32x4 hn;
#pragma unroll
        for (int e = 0; e < 4; ++e) {
            float r = sigmoid_f(g0[e] + sxs[e][tid] + shs[e][tid] + bh0[e]);
            float z = sigmoid_f(g1[e] + sxs[4 + e][tid] + shs[4 + e][tid] + bh1[e]);
            float n = tanh_f(g2[e] + sxs[8 + e][tid] + r * (shs[8 + e][tid] + bh2[e]));
            hn[e] = (1.f - z) * n + z * hold[e];
        }
        *(f32x4*)(h2all + ((size_t)(t * BB + tid)) * HH + j0) = hn;
    }
}

extern "C" void kernel_launch(void* const* d_in, const int* in_sizes, int n_in,
                              void* d_out, int out_size, void* d_ws, size_t ws_size,
                              hipStream_t stream)
{
    const int*   src  = (const int*)d_in[0];
    const int*   tgt  = (const int*)d_in[1];
    const float* eemb = (const float*)d_in[2];
    const float* ewih = (const float*)d_in[3];
    const float* ewhh = (const float*)d_in[4];
    const float* ebih = (const float*)d_in[5];
    const float* ebhh = (const float*)d_in[6];
    const float* wq   = (const float*)d_in[7];
    const float* bq   = (const float*)d_in[8];
    const float* wk   = (const float*)d_in[9];
    const float* bk   = (const float*)d_in[10];
    const float* wsv  = (const float*)d_in[11];
    const float* bsv  = (const float*)d_in[12];
    const float* demb = (const float*)d_in[13];
    const float* dwih = (const float*)d_in[14];
    const float* dwhh = (const float*)d_in[15];
    const float* dbih = (const float*)d_in[16];
    const float* dbhh = (const float*)d_in[17];
    const float* wo   = (const float*)d_in[18];
    const float* bo   = (const float*)d_in[19];
    float* out = (float*)d_out;

    float* w = (float*)d_ws;
    float* enc_gi  = w;                                 // [B*S][3H]
    float* dec_gi  = enc_gi  + (size_t)BB * SS * GG;    // [TD*B][3H]
    float* enc_out = dec_gi  + (size_t)TD * BB * GG;    // [B][S][H]
    float* keys    = enc_out + (size_t)BB * SS * HH;    // [B*S][H]
    float* h2all   = keys    + (size_t)BB * SS * HH;    // [TD][B][H]
    float* qbuf    = h2all   + (size_t)TD * BB * HH;    // [B][H]
    float* ctxbuf  = qbuf    + (size_t)BB * HH;         // [B][H]
    float* hsums   = ctxbuf  + (size_t)BB * HH;         // [256][12][32]
    int*   didx    = (int*)(hsums + (size_t)256 * 384); // [TD*B]

    float* attn_out = out + (size_t)BB * TD * VV;

    k_dec_idx<<<dim3((TD * BB + 255) / 256), 256, 0, stream>>>(tgt, didx);

    // enc_gi = gather(enc_embed)@enc_w_ih^T + b_ih
    k_gemm128<<<dim3(GG / 128, (BB * SS) / 128), 256, 0, stream>>>(
        eemb, ewih, ebih, enc_gi, src, BB * SS, GG, EE, EE, EE, GG, 0);
    // dec_gi = gather(dec_embed)@dec_w_ih[:, :E]^T + b_ih
    k_gemm128<<<dim3(GG / 128, (TD * BB + 127) / 128), 256, 0, stream>>>(
        demb, dwih, dbih, dec_gi, didx, TD * BB, GG, EE, EE, EE + HH, GG, 0);

    for (int s = 0; s < SS; ++s)
        k_enc_step<<<dim3(256), dim3(512), 0, stream>>>(
            enc_gi, ewhh, ebhh, enc_out, s);

    // keys = enc_out @ wk^T + bk
    k_gemm128<<<dim3(HH / 128, (BB * SS) / 128), 256, 0, stream>>>(
        enc_out, wk, bk, keys, nullptr, BB * SS, HH, HH, HH, HH, HH, 0);

    for (int t = 0; t < TD; ++t) {
        const float* hbase = (t == 0) ? enc_out + (size_t)(SS - 1) * HH
                                      : h2all + (size_t)(t - 1) * BB * HH;
        long hstride = (t == 0) ? (long)SS * HH : (long)HH;
        k_hq<<<dim3(256), dim3(512), 0, stream>>>(
            hbase, hstride, dwhh, wq, bq, qbuf, hsums);
        k_attn<<<dim3(BB), dim3(512), 0, stream>>>(
            qbuf, keys, wsv, bsv, src, enc_out, ctxbuf, attn_out, t);
        k_fin<<<dim3(256), dim3(512), 0, stream>>>(
            dec_gi, dwih, dbhh, ctxbuf, hsums, hbase, hstride, h2all, t);
    }

    // logits = h2all @ wo^T + bo, rows permuted (t*B+b) -> (b*TD+t)
    k_gemm128<<<dim3(VV / 128, (TD * BB + 127) / 128), 256, 0, stream>>>(
        h2all, wo, bo, out, nullptr, TD * BB, VV, HH, HH, HH, VV, 1);
}

// Round 9
// 5397.322 us; speedup vs baseline: 4.0857x; 1.0319x over previous
//
#include <hip/hip_runtime.h>

// Seq2Seq GRU + Bahdanau attention, fp32. B=32 S=64 T=48 E=512 H=1024 V=32000.
// R9: decoder restructured to 2 launches/step via the encproj trick:
//   ctx @ Wih^T == sum_s w_s * (enc_out[s] @ Wih^T)  (linearity)
// so precompute encproj = enc_out @ dec_w_ih[:,E:]^T once (GEMM, reuses the
// enc_gi buffer), and K2 = attention + weighted-sum + gate finalize in one
// kernel. Eliminates k_fin (47 launches + per-step Wih traffic).

#define BB 32
#define SS 64
#define TT 48
#define TD 47
#define EE 512
#define HH 1024
#define GG 3072
#define VV 32000
#define SOS_IDX 1

typedef float f32x4 __attribute__((ext_vector_type(4)));

static __device__ __forceinline__ float sigmoid_f(float x) {
    return 1.0f / (1.0f + __expf(-x));
}
static __device__ __forceinline__ float tanh_f(float x) {
    return 1.0f - 2.0f / (__expf(2.0f * x) + 1.0f);
}

__global__ void k_dec_idx(const int* __restrict__ tgt, int* __restrict__ idx) {
    int m = blockIdx.x * 256 + threadIdx.x;
    if (m < TD * BB) {
        int t = m >> 5, b = m & 31;
        idx[m] = (t == 0) ? SOS_IDX : tgt[b * TT + t];
    }
}

// ---------------- 128x128-tile fp32 GEMM ----------------
// C[m,n] = sum_k A[row(m),k] * Wt[n,k] + bias[n]; row(m)=rowidx?rowidx[m]:m.
// permute=1: output row = (m&31)*TD + (m>>5). N must be divisible by 128.
__global__ __launch_bounds__(256) void k_gemm128(
    const float* __restrict__ A, const float* __restrict__ Wt,
    const float* __restrict__ bias, float* __restrict__ C,
    const int* __restrict__ rowidx,
    int M, int N, int K, int lda, int ldw, int ldc, int permute)
{
    __shared__ __align__(16) float As[16][128];
    __shared__ __align__(16) float Bs[16][128];
    const int tid = threadIdx.x;
    const int tm = tid >> 4, tn = tid & 15;
    const int row0 = blockIdx.y * 128;
    const int col0 = blockIdx.x * 128;
    const int lr = tid >> 1;        // 0..127
    const int lq = tid & 1;         // k-half

    long arow_off = -1;
    {
        int arow = row0 + lr;
        if (arow < M) {
            int r = rowidx ? rowidx[arow] : arow;
            arow_off = (long)r * lda;
        }
    }
    const long wrow_off = (long)(col0 + lr) * ldw;

    float acc[8][8];
#pragma unroll
    for (int i = 0; i < 8; ++i)
#pragma unroll
        for (int j = 0; j < 8; ++j) acc[i][j] = 0.f;

    for (int k0 = 0; k0 < K; k0 += 16) {
        f32x4 av0 = {0.f,0.f,0.f,0.f}, av1 = {0.f,0.f,0.f,0.f};
        if (arow_off >= 0) {
            av0 = *(const f32x4*)(A + arow_off + k0 + lq * 8);
            av1 = *(const f32x4*)(A + arow_off + k0 + lq * 8 + 4);
        }
        f32x4 wv0 = *(const f32x4*)(Wt + wrow_off + k0 + lq * 8);
        f32x4 wv1 = *(const f32x4*)(Wt + wrow_off + k0 + lq * 8 + 4);
        __syncthreads();
#pragma unroll
        for (int i = 0; i < 4; ++i) {
            As[lq * 8 + i][lr] = av0[i];
            As[lq * 8 + 4 + i][lr] = av1[i];
            Bs[lq * 8 + i][lr] = wv0[i];
            Bs[lq * 8 + 4 + i][lr] = wv1[i];
        }
        __syncthreads();
#pragma unroll
        for (int kk = 0; kk < 16; ++kk) {
            f32x4 a0 = *(const f32x4*)&As[kk][tm * 4];
            f32x4 a1 = *(const f32x4*)&As[kk][64 + tm * 4];
            f32x4 b0 = *(const f32x4*)&Bs[kk][tn * 4];
            f32x4 b1 = *(const f32x4*)&Bs[kk][64 + tn * 4];
            float a[8], b[8];
#pragma unroll
            for (int i = 0; i < 4; ++i) {
                a[i] = a0[i]; a[4 + i] = a1[i];
                b[i] = b0[i]; b[4 + i] = b1[i];
            }
#pragma unroll
            for (int i = 0; i < 8; ++i)
#pragma unroll
                for (int j = 0; j < 8; ++j) acc[i][j] += a[i] * b[j];
        }
    }

    f32x4 bv0 = {0.f,0.f,0.f,0.f}, bv1 = {0.f,0.f,0.f,0.f};
    if (bias) {
        bv0 = *(const f32x4*)(bias + col0 + tn * 4);
        bv1 = *(const f32x4*)(bias + col0 + 64 + tn * 4);
    }
#pragma unroll
    for (int i = 0; i < 8; ++i) {
        int m = row0 + ((i < 4) ? (tm * 4 + i) : (64 + tm * 4 + i - 4));
        if (m >= M) continue;
        int orow = permute ? ((m & 31) * TD + (m >> 5)) : m;
        f32x4 v0, v1;
#pragma unroll
        for (int j = 0; j < 4; ++j) {
            v0[j] = acc[i][j] + bv0[j];
            v1[j] = acc[i][4 + j] + bv1[j];
        }
        *(f32x4*)(C + (long)orow * ldc + col0 + tn * 4) = v0;
        *(f32x4*)(C + (long)orow * ldc + col0 + 64 + tn * 4) = v1;
    }
}

// ---------------- encoder step (one launch per s) ----------------
__global__ __launch_bounds__(512, 2) void k_enc_step(
    const float* __restrict__ gi, const float* __restrict__ Whh,
    const float* __restrict__ bhh, float* __restrict__ enc_out, int s)
{
    __shared__ float red[12][16][32];
    __shared__ float sums[12][32];
    const int tid = threadIdx.x, bid = blockIdx.x;
    const int b = tid & 31, ks = tid >> 5;
    const int j0 = bid * 4;
    const int kc = ks * 64;

    float acc[12];
#pragma unroll
    for (int u = 0; u < 12; ++u) acc[u] = 0.f;
    if (s > 0) {
        f32x4 hreg[16];
        const float* hb = enc_out + ((size_t)b * SS + (s - 1)) * HH + kc;
#pragma unroll
        for (int i = 0; i < 16; ++i) hreg[i] = *(const f32x4*)(hb + (i << 2));
#pragma unroll
        for (int jj = 0; jj < 4; ++jj) {
            const float* pr = Whh + ((size_t)(j0 + jj) << 10) + kc;
            const float* pz = Whh + ((size_t)(HH + j0 + jj) << 10) + kc;
            const float* pn = Whh + ((size_t)(2 * HH + j0 + jj) << 10) + kc;
            float ar = 0.f, az = 0.f, an = 0.f;
#pragma unroll
            for (int i = 0; i < 16; ++i) {
                f32x4 h4 = hreg[i];
                f32x4 w;
                w = *(const f32x4*)(pr + (i << 2));
                ar += h4.x * w.x + h4.y * w.y + h4.z * w.z + h4.w * w.w;
                w = *(const f32x4*)(pz + (i << 2));
                az += h4.x * w.x + h4.y * w.y + h4.z * w.z + h4.w * w.w;
                w = *(const f32x4*)(pn + (i << 2));
                an += h4.x * w.x + h4.y * w.y + h4.z * w.z + h4.w * w.w;
            }
            acc[jj] = ar; acc[4 + jj] = az; acc[8 + jj] = an;
        }
    }
#pragma unroll
    for (int u = 0; u < 12; ++u) red[u][ks][b] = acc[u];
    __syncthreads();
    if (tid < 384) {
        int u = tid >> 5, fb = tid & 31;
        float x = 0.f;
#pragma unroll
        for (int q = 0; q < 16; ++q) x += red[u][q][fb];
        sums[u][fb] = x;
    }
    __syncthreads();
    if (tid < 32) {
        const f32x4 bh0 = *(const f32x4*)(bhh + j0);
        const f32x4 bh1 = *(const f32x4*)(bhh + HH + j0);
        const f32x4 bh2 = *(const f32x4*)(bhh + 2 * HH + j0);
        const float* gr = gi + (size_t)(tid * SS + s) * GG;
        f32x4 g0 = *(const f32x4*)(gr + j0);
        f32x4 g1 = *(const f32x4*)(gr + HH + j0);
        f32x4 g2 = *(const f32x4*)(gr + 2 * HH + j0);
        f32x4 hold = {0.f, 0.f, 0.f, 0.f};
        if (s > 0) hold = *(const f32x4*)(enc_out + ((size_t)tid * SS + (s - 1)) * HH + j0);
        f32x4 hn;
#pragma unroll
        for (int e = 0; e < 4; ++e) {
            float r = sigmoid_f(g0[e] + sums[e][tid] + bh0[e]);
            float z = sigmoid_f(g1[e] + sums[4 + e][tid] + bh1[e]);
            float n = tanh_f(g2[e] + r * (sums[8 + e][tid] + bh2[e]));
            hn[e] = (1.f - z) * n + z * hold[e];
        }
        *(f32x4*)(enc_out + ((size_t)tid * SS + s) * HH + j0) = hn;
    }
}

// ---------------- decoder K1: h-side dots + q ----------------
// 256 blocks x 512 thr. hsums layout [gate][b][j] (j-coalesced for K2 reads).
__global__ __launch_bounds__(512, 2) void k_hq(
    const float* __restrict__ hbase, long hstride,
    const float* __restrict__ Whh, const float* __restrict__ wq,
    const float* __restrict__ bq, float* __restrict__ qbuf,
    float* __restrict__ hsums)
{
    __shared__ float red[16][16][32];
    __shared__ float qsum[4][32];
    const int tid = threadIdx.x, bid = blockIdx.x;
    const int b = tid & 31, ks = tid >> 5;
    const int j0 = bid * 4;
    const int kc = ks * 64;

    f32x4 hreg[16];
    const float* hb = hbase + (size_t)b * hstride + kc;
#pragma unroll
    for (int i = 0; i < 16; ++i) hreg[i] = *(const f32x4*)(hb + (i << 2));
    float acc[16];
#pragma unroll
    for (int jj = 0; jj < 4; ++jj) {
        const float* pr = Whh + ((size_t)(j0 + jj) << 10) + kc;
        const float* pz = Whh + ((size_t)(HH + j0 + jj) << 10) + kc;
        const float* pn = Whh + ((size_t)(2 * HH + j0 + jj) << 10) + kc;
        const float* pq = wq + ((size_t)(j0 + jj) << 10) + kc;
        float ar = 0.f, az = 0.f, an = 0.f, aq = 0.f;
#pragma unroll
        for (int i = 0; i < 16; ++i) {
            f32x4 h4 = hreg[i];
            f32x4 w;
            w = *(const f32x4*)(pr + (i << 2));
            ar += h4.x * w.x + h4.y * w.y + h4.z * w.z + h4.w * w.w;
            w = *(const f32x4*)(pz + (i << 2));
            az += h4.x * w.x + h4.y * w.y + h4.z * w.z + h4.w * w.w;
            w = *(const f32x4*)(pn + (i << 2));
            an += h4.x * w.x + h4.y * w.y + h4.z * w.z + h4.w * w.w;
            w = *(const f32x4*)(pq + (i << 2));
            aq += h4.x * w.x + h4.y * w.y + h4.z * w.z + h4.w * w.w;
        }
        acc[jj] = ar; acc[4 + jj] = az; acc[8 + jj] = an; acc[12 + jj] = aq;
    }
#pragma unroll
    for (int u = 0; u < 16; ++u) red[u][ks][b] = acc[u];
    __syncthreads();
    {
        int u = tid >> 5, fb = tid & 31;
        float x = 0.f;
#pragma unroll
        for (int q = 0; q < 16; ++q) x += red[u][q][fb];
        if (u < 12) {
            int g = u >> 2, jj = u & 3;
            hsums[(size_t)g * BB * HH + (size_t)fb * HH + j0 + jj] = x;
        } else {
            qsum[u - 12][fb] = x;
        }
    }
    __syncthreads();
    if (tid < 32) {
        const f32x4 bq4 = *(const f32x4*)(bq + j0);
        f32x4 qv;
        qv.x = qsum[0][tid] + bq4.x;
        qv.y = qsum[1][tid] + bq4.y;
        qv.z = qsum[2][tid] + bq4.z;
        qv.w = qsum[3][tid] + bq4.w;
        *(f32x4*)(qbuf + (size_t)tid * HH + j0) = qv;
    }
}

// ---------------- decoder K2: attention + xsum + finalize ----------------
// 32 blocks (one per batch) x 512 thr.
__global__ __launch_bounds__(512, 2) void k_attn_fin(
    const float* __restrict__ qbuf, const float* __restrict__ keys,
    const float* __restrict__ wsv, const float* __restrict__ bsv,
    const int* __restrict__ src, const float* __restrict__ encproj,
    const float* __restrict__ gi, const float* __restrict__ bhh,
    const float* __restrict__ hsums, const float* __restrict__ hbase,
    long hstride, float* __restrict__ h2all, float* __restrict__ attn_out,
    int t)
{
    __shared__ float qs[HH];
    __shared__ float wss[HH];
    __shared__ float sc[8][64];
    __shared__ float wl[64];
    __shared__ float xls[GG];
    const int ab = blockIdx.x;
    const int tid = threadIdx.x;
    if (tid < 256) {
        *(f32x4*)&qs[tid * 4] = *(const f32x4*)(qbuf + (size_t)ab * HH + tid * 4);
        *(f32x4*)&wss[tid * 4] = *(const f32x4*)(wsv + tid * 4);
    }
    __syncthreads();
    // scores
    {
        const int s4 = tid >> 3, kq = tid & 7;
        const float* kr = keys + (size_t)(ab * SS + s4) * HH + kq * 128;
        float a = 0.f;
        for (int i = 0; i < 32; ++i) {
            f32x4 kv = *(const f32x4*)(kr + (i << 2));
            int k = kq * 128 + (i << 2);
            a += tanh_f(qs[k] + kv.x) * wss[k]
               + tanh_f(qs[k + 1] + kv.y) * wss[k + 1]
               + tanh_f(qs[k + 2] + kv.z) * wss[k + 2]
               + tanh_f(qs[k + 3] + kv.w) * wss[k + 3];
        }
        sc[kq][s4] = a;
    }
    __syncthreads();
    if (tid < 64) {
        float v = bsv[0];
#pragma unroll
        for (int q = 0; q < 8; ++q) v += sc[q][tid];
        bool valid = src[ab * SS + tid] != 0;
        float m = valid ? v : -3.0e38f;
        for (int off = 32; off; off >>= 1) m = fmaxf(m, __shfl_xor(m, off));
        float e = valid ? __expf(v - m) : 0.f;
        float ssum = e;
        for (int off = 32; off; off >>= 1) ssum += __shfl_xor(ssum, off);
        float wgt = e / ssum;
        wl[tid] = wgt;
        attn_out[((size_t)ab * TD + t) * SS + tid] = wgt;
    }
    __syncthreads();
    // xsum[3072] = sum_s wl[s] * encproj[ab, s, :]
    {
        float xa[6] = {0.f, 0.f, 0.f, 0.f, 0.f, 0.f};
        for (int s2 = 0; s2 < SS; ++s2) {
            float wgt = wl[s2];
            const float* ep = encproj + (size_t)(ab * SS + s2) * GG;
#pragma unroll
            for (int u = 0; u < 6; ++u)
                xa[u] += wgt * ep[u * 512 + tid];
        }
#pragma unroll
        for (int u = 0; u < 6; ++u) xls[u * 512 + tid] = xa[u];
    }
    __syncthreads();
    // finalize: 2 j per thread
    const float* gr = gi + (size_t)(t * BB + ab) * GG;
#pragma unroll
    for (int half = 0; half < 2; ++half) {
        int j = half * 512 + tid;
        float g0 = gr[j] + xls[j];
        float g1 = gr[HH + j] + xls[HH + j];
        float g2 = gr[2 * HH + j] + xls[2 * HH + j];
        float sh0 = hsums[(size_t)0 * BB * HH + (size_t)ab * HH + j];
        float sh1 = hsums[(size_t)1 * BB * HH + (size_t)ab * HH + j];
        float sh2 = hsums[(size_t)2 * BB * HH + (size_t)ab * HH + j];
        float r = sigmoid_f(g0 + sh0 + bhh[j]);
        float z = sigmoid_f(g1 + sh1 + bhh[HH + j]);
        float n = tanh_f(g2 + r * (sh2 + bhh[2 * HH + j]));
        float hold = hbase[(size_t)ab * hstride + j];
        h2all[((size_t)t * BB + ab) * HH + j] = (1.f - z) * n + z * hold;
    }
}

extern "C" void kernel_launch(void* const* d_in, const int* in_sizes, int n_in,
                              void* d_out, int out_size, void* d_ws, size_t ws_size,
                              hipStream_t stream)
{
    const int*   src  = (const int*)d_in[0];
    const int*   tgt  = (const int*)d_in[1];
    const float* eemb = (const float*)d_in[2];
    const float* ewih = (const float*)d_in[3];
    const float* ewhh = (const float*)d_in[4];
    const float* ebih = (const float*)d_in[5];
    const float* ebhh = (const float*)d_in[6];
    const float* wq   = (const float*)d_in[7];
    const float* bq   = (const float*)d_in[8];
    const float* wk   = (const float*)d_in[9];
    const float* bk   = (const float*)d_in[10];
    const float* wsv  = (const float*)d_in[11];
    const float* bsv  = (const float*)d_in[12];
    const float* demb = (const float*)d_in[13];
    const float* dwih = (const float*)d_in[14];
    const float* dwhh = (const float*)d_in[15];
    const float* dbih = (const float*)d_in[16];
    const float* dbhh = (const float*)d_in[17];
    const float* wo   = (const float*)d_in[18];
    const float* bo   = (const float*)d_in[19];
    float* out = (float*)d_out;

    float* w = (float*)d_ws;
    float* enc_gi  = w;                                 // [B*S][3H]; reused as encproj
    float* dec_gi  = enc_gi  + (size_t)BB * SS * GG;    // [TD*B][3H]
    float* enc_out = dec_gi  + (size_t)TD * BB * GG;    // [B][S][H]
    float* keys    = enc_out + (size_t)BB * SS * HH;    // [B*S][H]
    float* h2all   = keys    + (size_t)BB * SS * HH;    // [TD][B][H]
    float* qbuf    = h2all   + (size_t)TD * BB * HH;    // [B][H]
    float* hsums   = qbuf    + (size_t)BB * HH;         // [3][B][H]
    int*   didx    = (int*)(hsums + (size_t)3 * BB * HH); // [TD*B]

    float* encproj = enc_gi;   // overlap: enc_gi dead after encoder finishes

    float* attn_out = out + (size_t)BB * TD * VV;

    k_dec_idx<<<dim3((TD * BB + 255) / 256), 256, 0, stream>>>(tgt, didx);

    // enc_gi = gather(enc_embed)@enc_w_ih^T + b_ih
    k_gemm128<<<dim3(GG / 128, (BB * SS) / 128), 256, 0, stream>>>(
        eemb, ewih, ebih, enc_gi, src, BB * SS, GG, EE, EE, EE, GG, 0);
    // dec_gi = gather(dec_embed)@dec_w_ih[:, :E]^T + b_ih
    k_gemm128<<<dim3(GG / 128, (TD * BB + 127) / 128), 256, 0, stream>>>(
        demb, dwih, dbih, dec_gi, didx, TD * BB, GG, EE, EE, EE + HH, GG, 0);

    for (int s = 0; s < SS; ++s)
        k_enc_step<<<dim3(256), dim3(512), 0, stream>>>(
            enc_gi, ewhh, ebhh, enc_out, s);

    // keys = enc_out @ wk^T + bk
    k_gemm128<<<dim3(HH / 128, (BB * SS) / 128), 256, 0, stream>>>(
        enc_out, wk, bk, keys, nullptr, BB * SS, HH, HH, HH, HH, HH, 0);
    // encproj = enc_out @ dec_w_ih[:, E:]^T   (overwrites enc_gi — now dead)
    k_gemm128<<<dim3(GG / 128, (BB * SS) / 128), 256, 0, stream>>>(
        enc_out, dwih + EE, nullptr, encproj, nullptr,
        BB * SS, GG, HH, HH, EE + HH, GG, 0);

    for (int t = 0; t < TD; ++t) {
        const float* hbase = (t == 0) ? enc_out + (size_t)(SS - 1) * HH
                                      : h2all + (size_t)(t - 1) * BB * HH;
        long hstride = (t == 0) ? (long)SS * HH : (long)HH;
        k_hq<<<dim3(256), dim3(512), 0, stream>>>(
            hbase, hstride, dwhh, wq, bq, qbuf, hsums);
        k_attn_fin<<<dim3(BB), dim3(512), 0, stream>>>(
            qbuf, keys, wsv, bsv, src, encproj, dec_gi, dbhh, hsums,
            hbase, hstride, h2all, attn_out, t);
    }

    // logits = h2all @ wo^T + bo, rows permuted (t*B+b) -> (b*TD+t)
    k_gemm128<<<dim3(VV / 128, (TD * BB + 127) / 128), 256, 0, stream>>>(
        h2all, wo, bo, out, nullptr, TD * BB, VV, HH, HH, HH, VV, 1);
}

// Round 11
// 4495.337 us; speedup vs baseline: 4.9055x; 1.2006x over previous
//
#include <hip/hip_runtime.h>

// Seq2Seq GRU + Bahdanau attention, fp32. B=32 S=64 T=48 E=512 H=1024 V=32000.
// R11 = R10 with the k_gemm128 call-site arg-count fix (keys GEMM was missing
// its ldc). Logits GEMM -> split-bf16 MFMA: C = (A_hi + A_lo) @ bf16(wo)^T as
// one K'=2048 bf16 MFMA GEMM. Recurrence unchanged from R9.

#define BB 32
#define SS 64
#define TT 48
#define TD 47
#define EE 512
#define HH 1024
#define GG 3072
#define VV 32000
#define SOS_IDX 1
#define MPAD 1536          // 1504 rows padded to 12*128

typedef float f32x4 __attribute__((ext_vector_type(4)));
typedef short bf16x8 __attribute__((ext_vector_type(8)));

static __device__ __forceinline__ float sigmoid_f(float x) {
    return 1.0f / (1.0f + __expf(-x));
}
static __device__ __forceinline__ float tanh_f(float x) {
    return 1.0f - 2.0f / (__expf(2.0f * x) + 1.0f);
}
static __device__ __forceinline__ unsigned short f2bf(float f) {
    unsigned u = __float_as_uint(f);
    u = u + 0x7fffu + ((u >> 16) & 1u);
    return (unsigned short)(u >> 16);
}

__global__ void k_dec_idx(const int* __restrict__ tgt, int* __restrict__ idx) {
    int m = blockIdx.x * 256 + threadIdx.x;
    if (m < TD * BB) {
        int t = m >> 5, b = m & 31;
        idx[m] = (t == 0) ? SOS_IDX : tgt[b * TT + t];
    }
}

// ---------------- fp32 128x128 GEMM (non-logits projections) ----------------
__global__ __launch_bounds__(256) void k_gemm128(
    const float* __restrict__ A, const float* __restrict__ Wt,
    const float* __restrict__ bias, float* __restrict__ C,
    const int* __restrict__ rowidx,
    int M, int N, int K, int lda, int ldw, int ldc)
{
    __shared__ __align__(16) float As[16][128];
    __shared__ __align__(16) float Bs[16][128];
    const int tid = threadIdx.x;
    const int tm = tid >> 4, tn = tid & 15;
    const int row0 = blockIdx.y * 128;
    const int col0 = blockIdx.x * 128;
    const int lr = tid >> 1;
    const int lq = tid & 1;

    long arow_off = -1;
    {
        int arow = row0 + lr;
        if (arow < M) {
            int r = rowidx ? rowidx[arow] : arow;
            arow_off = (long)r * lda;
        }
    }
    const long wrow_off = (long)(col0 + lr) * ldw;

    float acc[8][8];
#pragma unroll
    for (int i = 0; i < 8; ++i)
#pragma unroll
        for (int j = 0; j < 8; ++j) acc[i][j] = 0.f;

    for (int k0 = 0; k0 < K; k0 += 16) {
        f32x4 av0 = {0.f,0.f,0.f,0.f}, av1 = {0.f,0.f,0.f,0.f};
        if (arow_off >= 0) {
            av0 = *(const f32x4*)(A + arow_off + k0 + lq * 8);
            av1 = *(const f32x4*)(A + arow_off + k0 + lq * 8 + 4);
        }
        f32x4 wv0 = *(const f32x4*)(Wt + wrow_off + k0 + lq * 8);
        f32x4 wv1 = *(const f32x4*)(Wt + wrow_off + k0 + lq * 8 + 4);
        __syncthreads();
#pragma unroll
        for (int i = 0; i < 4; ++i) {
            As[lq * 8 + i][lr] = av0[i];
            As[lq * 8 + 4 + i][lr] = av1[i];
            Bs[lq * 8 + i][lr] = wv0[i];
            Bs[lq * 8 + 4 + i][lr] = wv1[i];
        }
        __syncthreads();
#pragma unroll
        for (int kk = 0; kk < 16; ++kk) {
            f32x4 a0 = *(const f32x4*)&As[kk][tm * 4];
            f32x4 a1 = *(const f32x4*)&As[kk][64 + tm * 4];
            f32x4 b0 = *(const f32x4*)&Bs[kk][tn * 4];
            f32x4 b1 = *(const f32x4*)&Bs[kk][64 + tn * 4];
            float a[8], b[8];
#pragma unroll
            for (int i = 0; i < 4; ++i) {
                a[i] = a0[i]; a[4 + i] = a1[i];
                b[i] = b0[i]; b[4 + i] = b1[i];
            }
#pragma unroll
            for (int i = 0; i < 8; ++i)
#pragma unroll
                for (int j = 0; j < 8; ++j) acc[i][j] += a[i] * b[j];
        }
    }

    f32x4 bv0 = {0.f,0.f,0.f,0.f}, bv1 = {0.f,0.f,0.f,0.f};
    if (bias) {
        bv0 = *(const f32x4*)(bias + col0 + tn * 4);
        bv1 = *(const f32x4*)(bias + col0 + 64 + tn * 4);
    }
#pragma unroll
    for (int i = 0; i < 8; ++i) {
        int m = row0 + ((i < 4) ? (tm * 4 + i) : (64 + tm * 4 + i - 4));
        if (m >= M) continue;
        f32x4 v0, v1;
#pragma unroll
        for (int j = 0; j < 4; ++j) {
            v0[j] = acc[i][j] + bv0[j];
            v1[j] = acc[i][4 + j] + bv1[j];
        }
        *(f32x4*)(C + (long)m * ldc + col0 + tn * 4) = v0;
        *(f32x4*)(C + (long)m * ldc + col0 + 64 + tn * 4) = v1;
    }
}

// ---------------- conversions for split-bf16 logits ----------------
__global__ __launch_bounds__(256) void k_cvtA(
    const float* __restrict__ A, unsigned short* __restrict__ Ah,
    unsigned short* __restrict__ Al)
{
    size_t i4 = ((size_t)blockIdx.x * 256 + threadIdx.x) * 4;
    int row = (int)(i4 >> 10);
    f32x4 v = {0.f, 0.f, 0.f, 0.f};
    if (row < TD * BB) v = *(const f32x4*)(A + i4);
    ushort4 h, l;
    float hf;
    h.x = f2bf(v.x); hf = __uint_as_float((unsigned)h.x << 16); l.x = f2bf(v.x - hf);
    h.y = f2bf(v.y); hf = __uint_as_float((unsigned)h.y << 16); l.y = f2bf(v.y - hf);
    h.z = f2bf(v.z); hf = __uint_as_float((unsigned)h.z << 16); l.z = f2bf(v.z - hf);
    h.w = f2bf(v.w); hf = __uint_as_float((unsigned)h.w << 16); l.w = f2bf(v.w - hf);
    *(ushort4*)(Ah + i4) = h;
    *(ushort4*)(Al + i4) = l;
}

__global__ __launch_bounds__(256) void k_cvtB(
    const float* __restrict__ Bsrc, unsigned short* __restrict__ Bh)
{
    size_t i4 = ((size_t)blockIdx.x * 256 + threadIdx.x) * 4;
    f32x4 v = *(const f32x4*)(Bsrc + i4);
    ushort4 h;
    h.x = f2bf(v.x); h.y = f2bf(v.y); h.z = f2bf(v.z); h.w = f2bf(v.w);
    *(ushort4*)(Bh + i4) = h;
}

// ---------------- split-bf16 MFMA logits GEMM ----------------
// C[orow(m)][n] = sum_k (Ah+Al)[m][k] * Bh[n][k] + bo[n], K'=2048 concat.
// 128x128 tile, 4 waves (2x2 of 64x64), 16x16x32 bf16 MFMA, XOR-swizzled LDS.
__global__ __launch_bounds__(256) void k_mfma_logits(
    const unsigned short* __restrict__ Ah,   // [MPAD][1024]; Al at +MPAD*1024
    const unsigned short* __restrict__ Bh,   // [VV][1024]
    const float* __restrict__ bo, float* __restrict__ C)
{
    __shared__ __align__(16) unsigned short As[128 * 64];
    __shared__ __align__(16) unsigned short Bs[128 * 64];
    const int tid = threadIdx.x;
    const int m0 = blockIdx.y * 128;
    const int n0 = blockIdx.x * 128;
    const int r = tid >> 1, half = tid & 1;
    const int lane = tid & 63, wid = tid >> 6;
    const int wm = wid >> 1, wn = wid & 1;

    f32x4 acc[4][4];
#pragma unroll
    for (int i = 0; i < 4; ++i)
#pragma unroll
        for (int j = 0; j < 4; ++j) acc[i][j] = (f32x4){0.f, 0.f, 0.f, 0.f};

    char* AsB = (char*)As;
    char* BsB = (char*)Bs;
    const int lwb = r * 128 + half * 64;       // write base byte within tile
    const int swz = (r & 7) << 4;

    for (int kt = 0; kt < 32; ++kt) {
        const int kb = (kt & 15) * 64;                       // k-base (bf16 units)
        const unsigned short* Ap = Ah + ((kt >> 4) ? (size_t)MPAD * 1024 : 0)
                                 + (size_t)(m0 + r) * 1024 + kb + half * 32;
        const unsigned short* Bp = Bh + (size_t)(n0 + r) * 1024 + kb + half * 32;
        f32x4 a0 = *(const f32x4*)(Ap + 0);
        f32x4 a1 = *(const f32x4*)(Ap + 8);
        f32x4 a2 = *(const f32x4*)(Ap + 16);
        f32x4 a3 = *(const f32x4*)(Ap + 24);
        f32x4 b0 = *(const f32x4*)(Bp + 0);
        f32x4 b1 = *(const f32x4*)(Bp + 8);
        f32x4 b2 = *(const f32x4*)(Bp + 16);
        f32x4 b3 = *(const f32x4*)(Bp + 24);
        __syncthreads();
        *(f32x4*)(AsB + ((lwb + 0)  ^ swz)) = a0;
        *(f32x4*)(AsB + ((lwb + 16) ^ swz)) = a1;
        *(f32x4*)(AsB + ((lwb + 32) ^ swz)) = a2;
        *(f32x4*)(AsB + ((lwb + 48) ^ swz)) = a3;
        *(f32x4*)(BsB + ((lwb + 0)  ^ swz)) = b0;
        *(f32x4*)(BsB + ((lwb + 16) ^ swz)) = b1;
        *(f32x4*)(BsB + ((lwb + 32) ^ swz)) = b2;
        *(f32x4*)(BsB + ((lwb + 48) ^ swz)) = b3;
        __syncthreads();
#pragma unroll
        for (int ks = 0; ks < 2; ++ks) {
            bf16x8 af[4], bf[4];
#pragma unroll
            for (int u = 0; u < 4; ++u) {
                int ml = wm * 64 + u * 16 + (lane & 15);
                int byteA = ml * 128 + ks * 64 + ((lane >> 4) << 4);
                af[u] = *(const bf16x8*)(AsB + (byteA ^ ((ml & 7) << 4)));
                int nl = wn * 64 + u * 16 + (lane & 15);
                int byteB = nl * 128 + ks * 64 + ((lane >> 4) << 4);
                bf[u] = *(const bf16x8*)(BsB + (byteB ^ ((nl & 7) << 4)));
            }
#pragma unroll
            for (int mi = 0; mi < 4; ++mi)
#pragma unroll
                for (int ni = 0; ni < 4; ++ni)
                    acc[mi][ni] = __builtin_amdgcn_mfma_f32_16x16x32_bf16(
                        af[mi], bf[ni], acc[mi][ni], 0, 0, 0);
        }
    }

    const int cl = lane & 15, rq = lane >> 4;
#pragma unroll
    for (int ni = 0; ni < 4; ++ni) {
        int col = n0 + wn * 64 + ni * 16 + cl;
        float bias = bo[col];
#pragma unroll
        for (int mi = 0; mi < 4; ++mi) {
#pragma unroll
            for (int j = 0; j < 4; ++j) {
                int m = m0 + wm * 64 + mi * 16 + rq * 4 + j;
                if (m < TD * BB) {
                    int orow = (m & 31) * TD + (m >> 5);
                    C[(size_t)orow * VV + col] = acc[mi][ni][j] + bias;
                }
            }
        }
    }
}

// ---------------- encoder step ----------------
__global__ __launch_bounds__(512, 2) void k_enc_step(
    const float* __restrict__ gi, const float* __restrict__ Whh,
    const float* __restrict__ bhh, float* __restrict__ enc_out, int s)
{
    __shared__ float red[12][16][32];
    __shared__ float sums[12][32];
    const int tid = threadIdx.x, bid = blockIdx.x;
    const int b = tid & 31, ks = tid >> 5;
    const int j0 = bid * 4;
    const int kc = ks * 64;

    float acc[12];
#pragma unroll
    for (int u = 0; u < 12; ++u) acc[u] = 0.f;
    if (s > 0) {
        f32x4 hreg[16];
        const float* hb = enc_out + ((size_t)b * SS + (s - 1)) * HH + kc;
#pragma unroll
        for (int i = 0; i < 16; ++i) hreg[i] = *(const f32x4*)(hb + (i << 2));
#pragma unroll
        for (int jj = 0; jj < 4; ++jj) {
            const float* pr = Whh + ((size_t)(j0 + jj) << 10) + kc;
            const float* pz = Whh + ((size_t)(HH + j0 + jj) << 10) + kc;
            const float* pn = Whh + ((size_t)(2 * HH + j0 + jj) << 10) + kc;
            float ar = 0.f, az = 0.f, an = 0.f;
#pragma unroll
            for (int i = 0; i < 16; ++i) {
                f32x4 h4 = hreg[i];
                f32x4 w;
                w = *(const f32x4*)(pr + (i << 2));
                ar += h4.x * w.x + h4.y * w.y + h4.z * w.z + h4.w * w.w;
                w = *(const f32x4*)(pz + (i << 2));
                az += h4.x * w.x + h4.y * w.y + h4.z * w.z + h4.w * w.w;
                w = *(const f32x4*)(pn + (i << 2));
                an += h4.x * w.x + h4.y * w.y + h4.z * w.z + h4.w * w.w;
            }
            acc[jj] = ar; acc[4 + jj] = az; acc[8 + jj] = an;
        }
    }
#pragma unroll
    for (int u = 0; u < 12; ++u) red[u][ks][b] = acc[u];
    __syncthreads();
    if (tid < 384) {
        int u = tid >> 5, fb = tid & 31;
        float x = 0.f;
#pragma unroll
        for (int q = 0; q < 16; ++q) x += red[u][q][fb];
        sums[u][fb] = x;
    }
    __syncthreads();
    if (tid < 32) {
        const f32x4 bh0 = *(const f32x4*)(bhh + j0);
        const f32x4 bh1 = *(const f32x4*)(bhh + HH + j0);
        const f32x4 bh2 = *(const f32x4*)(bhh + 2 * HH + j0);
        const float* gr = gi + (size_t)(tid * SS + s) * GG;
        f32x4 g0 = *(const f32x4*)(gr + j0);
        f32x4 g1 = *(const f32x4*)(gr + HH + j0);
        f32x4 g2 = *(const f32x4*)(gr + 2 * HH + j0);
        f32x4 hold = {0.f, 0.f, 0.f, 0.f};
        if (s > 0) hold = *(const f32x4*)(enc_out + ((size_t)tid * SS + (s - 1)) * HH + j0);
        f32x4 hn;
#pragma unroll
        for (int e = 0; e < 4; ++e) {
            float r = sigmoid_f(g0[e] + sums[e][tid] + bh0[e]);
            float z = sigmoid_f(g1[e] + sums[4 + e][tid] + bh1[e]);
            float n = tanh_f(g2[e] + r * (sums[8 + e][tid] + bh2[e]));
            hn[e] = (1.f - z) * n + z * hold[e];
        }
        *(f32x4*)(enc_out + ((size_t)tid * SS + s) * HH + j0) = hn;
    }
}

// ---------------- decoder K1: h-side dots + q ----------------
__global__ __launch_bounds__(512, 2) void k_hq(
    const float* __restrict__ hbase, long hstride,
    const float* __restrict__ Whh, const float* __restrict__ wq,
    const float* __restrict__ bq, float* __restrict__ qbuf,
    float* __restrict__ hsums)
{
    __shared__ float red[16][16][32];
    __shared__ float qsum[4][32];
    const int tid = threadIdx.x, bid = blockIdx.x;
    const int b = tid & 31, ks = tid >> 5;
    const int j0 = bid * 4;
    const int kc = ks * 64;

    f32x4 hreg[16];
    const float* hb = hbase + (size_t)b * hstride + kc;
#pragma unroll
    for (int i = 0; i < 16; ++i) hreg[i] = *(const f32x4*)(hb + (i << 2));
    float acc[16];
#pragma unroll
    for (int jj = 0; jj < 4; ++jj) {
        const float* pr = Whh + ((size_t)(j0 + jj) << 10) + kc;
        const float* pz = Whh + ((size_t)(HH + j0 + jj) << 10) + kc;
        const float* pn = Whh + ((size_t)(2 * HH + j0 + jj) << 10) + kc;
        const float* pq = wq + ((size_t)(j0 + jj) << 10) + kc;
        float ar = 0.f, az = 0.f, an = 0.f, aq = 0.f;
#pragma unroll
        for (int i = 0; i < 16; ++i) {
            f32x4 h4 = hreg[i];
            f32x4 w;
            w = *(const f32x4*)(pr + (i << 2));
            ar += h4.x * w.x + h4.y * w.y + h4.z * w.z + h4.w * w.w;
            w = *(const f32x4*)(pz + (i << 2));
            az += h4.x * w.x + h4.y * w.y + h4.z * w.z + h4.w * w.w;
            w = *(const f32x4*)(pn + (i << 2));
            an += h4.x * w.x + h4.y * w.y + h4.z * w.z + h4.w * w.w;
            w = *(const f32x4*)(pq + (i << 2));
            aq += h4.x * w.x + h4.y * w.y + h4.z * w.z + h4.w * w.w;
        }
        acc[jj] = ar; acc[4 + jj] = az; acc[8 + jj] = an; acc[12 + jj] = aq;
    }
#pragma unroll
    for (int u = 0; u < 16; ++u) red[u][ks][b] = acc[u];
    __syncthreads();
    {
        int u = tid >> 5, fb = tid & 31;
        float x = 0.f;
#pragma unroll
        for (int q = 0; q < 16; ++q) x += red[u][q][fb];
        if (u < 12) {
            int g = u >> 2, jj = u & 3;
            hsums[(size_t)g * BB * HH + (size_t)fb * HH + j0 + jj] = x;
        } else {
            qsum[u - 12][fb] = x;
        }
    }
    __syncthreads();
    if (tid < 32) {
        const f32x4 bq4 = *(const f32x4*)(bq + j0);
        f32x4 qv;
        qv.x = qsum[0][tid] + bq4.x;
        qv.y = qsum[1][tid] + bq4.y;
        qv.z = qsum[2][tid] + bq4.z;
        qv.w = qsum[3][tid] + bq4.w;
        *(f32x4*)(qbuf + (size_t)tid * HH + j0) = qv;
    }
}

// ---------------- decoder K2: attention + xsum + finalize ----------------
__global__ __launch_bounds__(512, 2) void k_attn_fin(
    const float* __restrict__ qbuf, const float* __restrict__ keys,
    const float* __restrict__ wsv, const float* __restrict__ bsv,
    const int* __restrict__ src, const float* __restrict__ encproj,
    const float* __restrict__ gi, const float* __restrict__ bhh,
    const float* __restrict__ hsums, const float* __restrict__ hbase,
    long hstride, float* __restrict__ h2all, float* __restrict__ attn_out,
    int t)
{
    __shared__ float qs[HH];
    __shared__ float wss[HH];
    __shared__ float sc[8][64];
    __shared__ float wl[64];
    __shared__ float xls[GG];
    const int ab = blockIdx.x;
    const int tid = threadIdx.x;
    if (tid < 256) {
        *(f32x4*)&qs[tid * 4] = *(const f32x4*)(qbuf + (size_t)ab * HH + tid * 4);
        *(f32x4*)&wss[tid * 4] = *(const f32x4*)(wsv + tid * 4);
    }
    __syncthreads();
    {
        const int s4 = tid >> 3, kq = tid & 7;
        const float* kr = keys + (size_t)(ab * SS + s4) * HH + kq * 128;
        float a = 0.f;
        for (int i = 0; i < 32; ++i) {
            f32x4 kv = *(const f32x4*)(kr + (i << 2));
            int k = kq * 128 + (i << 2);
            a += tanh_f(qs[k] + kv.x) * wss[k]
               + tanh_f(qs[k + 1] + kv.y) * wss[k + 1]
               + tanh_f(qs[k + 2] + kv.z) * wss[k + 2]
               + tanh_f(qs[k + 3] + kv.w) * wss[k + 3];
        }
        sc[kq][s4] = a;
    }
    __syncthreads();
    if (tid < 64) {
        float v = bsv[0];
#pragma unroll
        for (int q = 0; q < 8; ++q) v += sc[q][tid];
        bool valid = src[ab * SS + tid] != 0;
        float m = valid ? v : -3.0e38f;
        for (int off = 32; off; off >>= 1) m = fmaxf(m, __shfl_xor(m, off));
        float e = valid ? __expf(v - m) : 0.f;
        float ssum = e;
        for (int off = 32; off; off >>= 1) ssum += __shfl_xor(ssum, off);
        float wgt = e / ssum;
        wl[tid] = wgt;
        attn_out[((size_t)ab * TD + t) * SS + tid] = wgt;
    }
    __syncthreads();
    {
        float xa[6] = {0.f, 0.f, 0.f, 0.f, 0.f, 0.f};
        for (int s2 = 0; s2 < SS; ++s2) {
            float wgt = wl[s2];
            const float* ep = encproj + (size_t)(ab * SS + s2) * GG;
#pragma unroll
            for (int u = 0; u < 6; ++u)
                xa[u] += wgt * ep[u * 512 + tid];
        }
#pragma unroll
        for (int u = 0; u < 6; ++u) xls[u * 512 + tid] = xa[u];
    }
    __syncthreads();
    const float* gr = gi + (size_t)(t * BB + ab) * GG;
#pragma unroll
    for (int half = 0; half < 2; ++half) {
        int j = half * 512 + tid;
        float g0 = gr[j] + xls[j];
        float g1 = gr[HH + j] + xls[HH + j];
        float g2 = gr[2 * HH + j] + xls[2 * HH + j];
        float sh0 = hsums[(size_t)0 * BB * HH + (size_t)ab * HH + j];
        float sh1 = hsums[(size_t)1 * BB * HH + (size_t)ab * HH + j];
        float sh2 = hsums[(size_t)2 * BB * HH + (size_t)ab * HH + j];
        float r = sigmoid_f(g0 + sh0 + bhh[j]);
        float z = sigmoid_f(g1 + sh1 + bhh[HH + j]);
        float n = tanh_f(g2 + r * (sh2 + bhh[2 * HH + j]));
        float hold = hbase[(size_t)ab * hstride + j];
        h2all[((size_t)t * BB + ab) * HH + j] = (1.f - z) * n + z * hold;
    }
}

extern "C" void kernel_launch(void* const* d_in, const int* in_sizes, int n_in,
                              void* d_out, int out_size, void* d_ws, size_t ws_size,
                              hipStream_t stream)
{
    const int*   src  = (const int*)d_in[0];
    const int*   tgt  = (const int*)d_in[1];
    const float* eemb = (const float*)d_in[2];
    const float* ewih = (const float*)d_in[3];
    const float* ewhh = (const float*)d_in[4];
    const float* ebih = (const float*)d_in[5];
    const float* ebhh = (const float*)d_in[6];
    const float* wq   = (const float*)d_in[7];
    const float* bq   = (const float*)d_in[8];
    const float* wk   = (const float*)d_in[9];
    const float* bk   = (const float*)d_in[10];
    const float* wsv  = (const float*)d_in[11];
    const float* bsv  = (const float*)d_in[12];
    const float* demb = (const float*)d_in[13];
    const float* dwih = (const float*)d_in[14];
    const float* dwhh = (const float*)d_in[15];
    const float* dbih = (const float*)d_in[16];
    const float* dbhh = (const float*)d_in[17];
    const float* wo   = (const float*)d_in[18];
    const float* bo   = (const float*)d_in[19];
    float* out = (float*)d_out;

    float* w = (float*)d_ws;
    float* enc_gi  = w;                                 // [B*S][3H]; later encproj
    float* dec_gi  = enc_gi  + (size_t)BB * SS * GG;    // [TD*B][3H]
    float* enc_out = dec_gi  + (size_t)TD * BB * GG;    // [B][S][H]
    float* keys    = enc_out + (size_t)BB * SS * HH;    // [B*S][H]
    float* h2all   = keys    + (size_t)BB * SS * HH;    // [TD][B][H]
    float* qbuf    = h2all   + (size_t)TD * BB * HH;    // [B][H]
    float* hsums   = qbuf    + (size_t)BB * HH;         // [3][B][H]
    int*   didx    = (int*)(hsums + (size_t)3 * BB * HH); // [TD*B]
    unsigned short* Ah = (unsigned short*)(didx + TD * BB + 32); // [MPAD][1024]
    unsigned short* Al = Ah + (size_t)MPAD * 1024;
    // Bh overlays enc_gi..h2all (65.54 MB < 66.59 MB), valid only after decoder.
    unsigned short* Bh = (unsigned short*)w;

    float* encproj = enc_gi;   // overlap: enc_gi dead after encoder finishes
    float* attn_out = out + (size_t)BB * TD * VV;

    k_dec_idx<<<dim3((TD * BB + 255) / 256), 256, 0, stream>>>(tgt, didx);

    k_gemm128<<<dim3(GG / 128, (BB * SS) / 128), 256, 0, stream>>>(
        eemb, ewih, ebih, enc_gi, src, BB * SS, GG, EE, EE, EE, GG);
    k_gemm128<<<dim3(GG / 128, (TD * BB + 127) / 128), 256, 0, stream>>>(
        demb, dwih, dbih, dec_gi, didx, TD * BB, GG, EE, EE, EE + HH, GG);

    for (int s = 0; s < SS; ++s)
        k_enc_step<<<dim3(256), dim3(512), 0, stream>>>(
            enc_gi, ewhh, ebhh, enc_out, s);

    k_gemm128<<<dim3(HH / 128, (BB * SS) / 128), 256, 0, stream>>>(
        enc_out, wk, bk, keys, nullptr, BB * SS, HH, HH, HH, HH, HH);
    k_gemm128<<<dim3(GG / 128, (BB * SS) / 128), 256, 0, stream>>>(
        enc_out, dwih + EE, nullptr, encproj, nullptr,
        BB * SS, GG, HH, HH, EE + HH, GG);

    for (int t = 0; t < TD; ++t) {
        const float* hbase = (t == 0) ? enc_out + (size_t)(SS - 1) * HH
                                      : h2all + (size_t)(t - 1) * BB * HH;
        long hstride = (t == 0) ? (long)SS * HH : (long)HH;
        k_hq<<<dim3(256), dim3(512), 0, stream>>>(
            hbase, hstride, dwhh, wq, bq, qbuf, hsums);
        k_attn_fin<<<dim3(BB), dim3(512), 0, stream>>>(
            qbuf, keys, wsv, bsv, src, encproj, dec_gi, dbhh, hsums,
            hbase, hstride, h2all, attn_out, t);
    }

    // split-bf16 logits: h2all -> Ah/Al; wo -> Bh (overlay, after cvtA); MFMA.
    k_cvtA<<<dim3(MPAD * 1024 / 1024), 256, 0, stream>>>(h2all, Ah, Al);
    k_cvtB<<<dim3(VV * 1024 / 1024), 256, 0, stream>>>(wo, Bh);
    k_mfma_logits<<<dim3(VV / 128, MPAD / 128), 256, 0, stream>>>(
        Ah, Bh, bo, out);
}